// Round 1
// baseline (433.478 us; speedup 1.0000x reference)
//
#include <hip/hip_runtime.h>
#include <math.h>

#define EPS   1e-5f
#define NQ    12
#define DEPTH 3
#define BATCH 512
#define DIM   4096   // 2^NQ

__device__ inline float2 cmul(float2 a, float2 b) {
    return make_float2(a.x*b.x - a.y*b.y, a.x*b.y + a.y*b.x);
}
__device__ inline float2 cadd(float2 a, float2 b) {
    return make_float2(a.x + b.x, a.y + b.y);
}

// ---------------------------------------------------------------------------
// Precompute U = Rz@Ry@Rx for both layers (2*3*12 matrices, 4 complex each)
// and CRY (cos,sin) pairs (2*3*11).
// ---------------------------------------------------------------------------
__global__ void consts_kernel(const float* __restrict__ rot0, const float* __restrict__ ent0,
                              const float* __restrict__ rot1, const float* __restrict__ ent1,
                              float2* __restrict__ Uc, float2* __restrict__ Cc) {
    int t = threadIdx.x;
    if (t < 72) {
        int layer = t / 36, rem = t % 36, d = rem / 12, q = rem % 12;
        const float* rot = layer ? rot1 : rot0;
        float hx = 0.5f * rot[(d*NQ + q)*3 + 0];
        float hy = 0.5f * rot[(d*NQ + q)*3 + 1];
        float hz = 0.5f * rot[(d*NQ + q)*3 + 2];
        float cx = cosf(hx), sx = sinf(hx);
        float cy = cosf(hy), sy = sinf(hy);
        // M1 = Ry @ Rx
        float2 m00 = make_float2( cy*cx,  sy*sx);
        float2 m01 = make_float2(-sy*cx, -cy*sx);
        float2 m10 = make_float2( sy*cx, -cy*sx);
        float2 m11 = make_float2( cy*cx, -sy*sx);
        float2 ez  = make_float2(cosf(hz), -sinf(hz));   // e^{-i hz}
        float2 ezc = make_float2(ez.x, -ez.y);           // e^{+i hz}
        float2* U = Uc + t*4;   // index = layer*36 + d*12 + q
        U[0] = cmul(ez,  m00);
        U[1] = cmul(ez,  m01);
        U[2] = cmul(ezc, m10);
        U[3] = cmul(ezc, m11);
    } else if (t < 72 + 66) {
        int idx = t - 72, layer = idx / 33, rem = idx % 33;
        const float* ent = layer ? ent1 : ent0;
        float th = 0.5f * ent[rem];
        Cc[idx] = make_float2(cosf(th), sinf(th));
    }
}

// ---------------------------------------------------------------------------
// Encode: Y[:,q] = X @ We[q] + be[q]; BN over batch (block == column q);
// tanh; write A (B x NQ). X indexed as X[b*rs + i*cs] so the transposed
// inter-layer buffer works too.
// ---------------------------------------------------------------------------
__global__ __launch_bounds__(512) void encode_kernel(
        const float* __restrict__ X, int rs, int cs,
        const float* __restrict__ We, const float* __restrict__ be,
        const float* __restrict__ gi, const float* __restrict__ bi,
        float* __restrict__ A) {
    int q = blockIdx.x, b = threadIdx.x;
    __shared__ float w[512];
    __shared__ float2 red[8];
    w[b] = We[q*512 + b];
    __syncthreads();
    const float* xr = X + (size_t)b * rs;
    float acc = 0.f;
    #pragma unroll 8
    for (int i = 0; i < 512; ++i) acc += xr[(size_t)i * cs] * w[i];
    acc += be[q];

    float2 v = make_float2(acc, acc*acc);
    int lane = b & 63, wave = b >> 6;
    for (int off = 32; off; off >>= 1) { v.x += __shfl_down(v.x, off); v.y += __shfl_down(v.y, off); }
    if (lane == 0) red[wave] = v;
    __syncthreads();
    float s = 0.f, s2 = 0.f;
    #pragma unroll
    for (int wv = 0; wv < 8; ++wv) { s += red[wv].x; s2 += red[wv].y; }
    float mu  = s  * (1.f/512.f);
    float var = s2 * (1.f/512.f) - mu*mu;
    float val = (acc - mu) * rsqrtf(var + EPS) * gi[q] + bi[q];
    A[b*NQ + q] = tanhf(val);
}

// ---------------------------------------------------------------------------
// Quantum sim: one block per sample, state in LDS. Product-state init fused
// with depth-0 single-qubit rotations; then CRY chain + (depth 1,2) gates.
// ---------------------------------------------------------------------------
__global__ __launch_bounds__(256) void qsim_kernel(
        const float* __restrict__ A, const float2* __restrict__ UcAll,
        const float2* __restrict__ CcAll, int layer, float* __restrict__ mout) {
    int b = blockIdx.x, tid = threadIdx.x;
    const float2* Uc = UcAll + layer * DEPTH * NQ * 4;
    const float2* Cc = CcAll + layer * DEPTH * (NQ - 1);
    __shared__ float2 s[DIM];
    __shared__ float red[NQ * 4];

    // --- per-qubit init vectors (encode RY fused with depth-0 rotation U) ---
    float av[NQ]; float n2 = 0.f;
    #pragma unroll
    for (int q = 0; q < NQ; ++q) { av[q] = A[b*NQ + q]; n2 += av[q]*av[q]; }
    float scn = (n2 > 0.f) ? rsqrtf(n2) : 1.f;
    float2 v0[NQ], v1[NQ];
    #pragma unroll
    for (int q = 0; q < NQ; ++q) {
        float a  = av[q] * scn;
        float si = fminf(fabsf(a), 1.f);
        float c  = sqrtf(fmaxf(1.f - si*si, 0.f));
        float ss = (a < 0.f) ? -si : si;
        const float2* U = Uc + q*4;   // d = 0
        v0[q] = make_float2(U[0].x*c + U[1].x*ss, U[0].y*c + U[1].y*ss);
        v1[q] = make_float2(U[2].x*c + U[3].x*ss, U[2].y*c + U[3].y*ss);
    }
    // --- product-state init: amp[i] = prod_q (bit_q(i) ? v1 : v0) ---
    int hi = tid * 16;
    float2 common = make_float2(1.f, 0.f);
    #pragma unroll
    for (int q = 0; q < 8; ++q)
        common = cmul(common, ((hi >> (11 - q)) & 1) ? v1[q] : v0[q]);
    #pragma unroll
    for (int k = 0; k < 16; ++k) {
        float2 amp = common;
        #pragma unroll
        for (int q = 8; q < NQ; ++q)
            amp = cmul(amp, ((k >> (11 - q)) & 1) ? v1[q] : v0[q]);
        s[hi + k] = amp;
    }
    __syncthreads();

    for (int d = 0; d < DEPTH; ++d) {
        if (d > 0) {
            for (int q = 0; q < NQ; ++q) {
                const float2 u00 = Uc[(d*NQ+q)*4+0], u01 = Uc[(d*NQ+q)*4+1];
                const float2 u10 = Uc[(d*NQ+q)*4+2], u11 = Uc[(d*NQ+q)*4+3];
                int shift = 11 - q, st = 1 << shift;
                #pragma unroll
                for (int pp = 0; pp < 8; ++pp) {
                    int p  = tid + pp*256;
                    int i0 = ((p >> shift) << (shift + 1)) | (p & (st - 1));
                    int i1 = i0 | st;
                    float2 a0 = s[i0], a1 = s[i1];
                    s[i0] = cadd(cmul(u00, a0), cmul(u01, a1));
                    s[i1] = cadd(cmul(u10, a0), cmul(u11, a1));
                }
                __syncthreads();
            }
        }
        for (int i = 0; i < NQ - 1; ++i) {
            float2 cs_ = Cc[d*(NQ-1) + i];
            float co = cs_.x, si = cs_.y;
            int tshift = 10 - i;
            int lowmask = (1 << tshift) - 1;
            #pragma unroll
            for (int pp = 0; pp < 4; ++pp) {
                int p  = tid + pp*256;
                int i0 = ((p >> tshift) << (tshift + 2)) | (1 << (tshift + 1)) | (p & lowmask);
                int i1 = i0 | (1 << tshift);
                float2 a0 = s[i0], a1 = s[i1];
                s[i0] = make_float2(co*a0.x - si*a1.x, co*a0.y - si*a1.y);
                s[i1] = make_float2(si*a0.x + co*a1.x, si*a0.y + co*a1.y);
            }
            __syncthreads();
        }
    }

    // --- measurement: P(qubit q == 1) ---
    float msum = 0.f, p8 = 0.f, p9 = 0.f, p10 = 0.f, p11 = 0.f;
    #pragma unroll
    for (int k = 0; k < 16; ++k) {
        float2 a = s[hi + k];
        float mag = a.x*a.x + a.y*a.y;
        msum += mag;
        if (k & 8) p8  += mag;
        if (k & 4) p9  += mag;
        if (k & 2) p10 += mag;
        if (k & 1) p11 += mag;
    }
    float pq[NQ];
    #pragma unroll
    for (int q = 0; q < 8; ++q) pq[q] = ((tid >> (7 - q)) & 1) ? msum : 0.f;
    pq[8] = p8; pq[9] = p9; pq[10] = p10; pq[11] = p11;
    int lane = tid & 63, wave = tid >> 6;
    #pragma unroll
    for (int q = 0; q < NQ; ++q) {
        float v = pq[q];
        for (int off = 32; off; off >>= 1) v += __shfl_down(v, off);
        if (lane == 0) red[q*4 + wave] = v;
    }
    __syncthreads();
    if (tid < NQ)
        mout[b*NQ + tid] = red[tid*4] + red[tid*4+1] + red[tid*4+2] + red[tid*4+3];
}

// ---------------------------------------------------------------------------
// Decode: Z[:,h] = m @ Wd[h] + bd[h]; BN over batch (block == column h);
// write TRANSPOSED (H x B) so next layer's reads/writes coalesce.
// ---------------------------------------------------------------------------
__global__ __launch_bounds__(512) void decode_kernel(
        const float* __restrict__ m, const float* __restrict__ Wd,
        const float* __restrict__ bd, const float* __restrict__ go,
        const float* __restrict__ bo, float* __restrict__ outT) {
    int h = blockIdx.x, b = threadIdx.x;
    __shared__ float sm[BATCH * NQ];
    __shared__ float2 red[8];
    for (int idx = b; idx < BATCH * NQ; idx += 512) sm[idx] = m[idx];
    __syncthreads();
    float z = bd[h];
    #pragma unroll
    for (int q = 0; q < NQ; ++q) z += sm[b*NQ + q] * Wd[h*NQ + q];

    float2 v = make_float2(z, z*z);
    int lane = b & 63, wave = b >> 6;
    for (int off = 32; off; off >>= 1) { v.x += __shfl_down(v.x, off); v.y += __shfl_down(v.y, off); }
    if (lane == 0) red[wave] = v;
    __syncthreads();
    float s = 0.f, s2 = 0.f;
    #pragma unroll
    for (int wv = 0; wv < 8; ++wv) { s += red[wv].x; s2 += red[wv].y; }
    float mu  = s  * (1.f/512.f);
    float var = s2 * (1.f/512.f) - mu*mu;
    outT[(size_t)h*BATCH + b] = (z - mu) * rsqrtf(var + EPS) * go[h] + bo[h];
}

// ---------------------------------------------------------------------------
// SGEMM 1: C(512x1024) = A^T-stored(512k x 512b) x W2(1024x512)^T + b2
// Tile BM=64, BN=32, BK=32. grid (8, 32).
// ---------------------------------------------------------------------------
__global__ __launch_bounds__(256) void gemm1_kernel(
        const float* __restrict__ AT,   // (K=512, B=512), k-major
        const float* __restrict__ W,    // (N=1024, K=512)
        const float* __restrict__ bias,
        float* __restrict__ Cmat) {     // (512, 1024)
    __shared__ float As[32][64];
    __shared__ float Bs[32][33];
    int b0 = blockIdx.x * 64, j0 = blockIdx.y * 32;
    int tid = threadIdx.x;
    int tr = tid >> 4, tc = tid & 15;
    float acc[4][2] = {};
    for (int k0 = 0; k0 < 512; k0 += 32) {
        #pragma unroll
        for (int l = 0; l < 2; ++l) {
            int idx = tid + l*256;                 // [0,512) float4 slots
            int kk = idx >> 4, f4 = idx & 15;
            float4 vv = *(const float4*)(AT + (size_t)(k0 + kk)*512 + b0 + f4*4);
            *(float4*)(&As[kk][f4*4]) = vv;
        }
        {
            int jj = tid >> 3, kkb = (tid & 7) * 4;
            float4 vv = *(const float4*)(W + (size_t)(j0 + jj)*512 + k0 + kkb);
            Bs[kkb+0][jj] = vv.x; Bs[kkb+1][jj] = vv.y;
            Bs[kkb+2][jj] = vv.z; Bs[kkb+3][jj] = vv.w;
        }
        __syncthreads();
        #pragma unroll
        for (int kk = 0; kk < 32; ++kk) {
            float a0 = As[kk][tr*4+0], a1 = As[kk][tr*4+1];
            float a2 = As[kk][tr*4+2], a3 = As[kk][tr*4+3];
            float bb0 = Bs[kk][tc*2+0], bb1 = Bs[kk][tc*2+1];
            acc[0][0] += a0*bb0; acc[0][1] += a0*bb1;
            acc[1][0] += a1*bb0; acc[1][1] += a1*bb1;
            acc[2][0] += a2*bb0; acc[2][1] += a2*bb1;
            acc[3][0] += a3*bb0; acc[3][1] += a3*bb1;
        }
        __syncthreads();
    }
    float2 bia = *(const float2*)(bias + j0 + tc*2);
    #pragma unroll
    for (int r = 0; r < 4; ++r) {
        int bb = b0 + tr*4 + r;
        float2 o = make_float2(acc[r][0] + bia.x, acc[r][1] + bia.y);
        *(float2*)(Cmat + (size_t)bb*1024 + j0 + tc*2) = o;
    }
}

// ---------------------------------------------------------------------------
// SGEMM 2: C(512x256) = A(512x1024) x Wo(256x1024)^T + bo
// Tile BM=32, BN=32, BK=32. grid (16, 8).
// ---------------------------------------------------------------------------
__global__ __launch_bounds__(256) void gemm2_kernel(
        const float* __restrict__ Amat, // (512, 1024) row-major
        const float* __restrict__ W,    // (256, 1024)
        const float* __restrict__ bias,
        float* __restrict__ Cmat) {     // (512, 256)
    __shared__ float As[32][33];
    __shared__ float Bs[32][33];
    int b0 = blockIdx.x * 32, j0 = blockIdx.y * 32;
    int tid = threadIdx.x;
    int tr = tid >> 4, tc = tid & 15;
    float acc[2][2] = {};
    for (int k0 = 0; k0 < 1024; k0 += 32) {
        {
            int rr = tid >> 3, kkb = (tid & 7) * 4;
            float4 av = *(const float4*)(Amat + (size_t)(b0 + rr)*1024 + k0 + kkb);
            As[kkb+0][rr] = av.x; As[kkb+1][rr] = av.y;
            As[kkb+2][rr] = av.z; As[kkb+3][rr] = av.w;
            float4 wv = *(const float4*)(W + (size_t)(j0 + rr)*1024 + k0 + kkb);
            Bs[kkb+0][rr] = wv.x; Bs[kkb+1][rr] = wv.y;
            Bs[kkb+2][rr] = wv.z; Bs[kkb+3][rr] = wv.w;
        }
        __syncthreads();
        #pragma unroll
        for (int kk = 0; kk < 32; ++kk) {
            float a0 = As[kk][tr*2+0], a1 = As[kk][tr*2+1];
            float bb0 = Bs[kk][tc*2+0], bb1 = Bs[kk][tc*2+1];
            acc[0][0] += a0*bb0; acc[0][1] += a0*bb1;
            acc[1][0] += a1*bb0; acc[1][1] += a1*bb1;
        }
        __syncthreads();
    }
    float2 bia = *(const float2*)(bias + j0 + tc*2);
    #pragma unroll
    for (int r = 0; r < 2; ++r) {
        int bb = b0 + tr*2 + r;
        float2 o = make_float2(acc[r][0] + bia.x, acc[r][1] + bia.y);
        *(float2*)(Cmat + (size_t)bb*256 + j0 + tc*2) = o;
    }
}

// ---------------------------------------------------------------------------
// LayerNorm (+ReLU) over rows of 1024
// ---------------------------------------------------------------------------
__global__ __launch_bounds__(256) void ln_relu_kernel(
        const float* __restrict__ X, const float* __restrict__ g,
        const float* __restrict__ be, float* __restrict__ Y) {
    int b = blockIdx.x, tid = threadIdx.x;
    __shared__ float2 red[4];
    const float* xr = X + (size_t)b * 1024;
    float v0 = xr[tid], v1 = xr[tid+256], v2 = xr[tid+512], v3 = xr[tid+768];
    float2 v = make_float2(v0+v1+v2+v3, v0*v0+v1*v1+v2*v2+v3*v3);
    int lane = tid & 63, wave = tid >> 6;
    for (int off = 32; off; off >>= 1) { v.x += __shfl_down(v.x, off); v.y += __shfl_down(v.y, off); }
    if (lane == 0) red[wave] = v;
    __syncthreads();
    float s = 0.f, s2 = 0.f;
    #pragma unroll
    for (int wv = 0; wv < 4; ++wv) { s += red[wv].x; s2 += red[wv].y; }
    float mu  = s  * (1.f/1024.f);
    float var = s2 * (1.f/1024.f) - mu*mu;
    float inv = rsqrtf(var + EPS);
    float* yr = Y + (size_t)b * 1024;
    yr[tid]     = fmaxf((v0-mu)*inv*g[tid]     + be[tid],     0.f);
    yr[tid+256] = fmaxf((v1-mu)*inv*g[tid+256] + be[tid+256], 0.f);
    yr[tid+512] = fmaxf((v2-mu)*inv*g[tid+512] + be[tid+512], 0.f);
    yr[tid+768] = fmaxf((v3-mu)*inv*g[tid+768] + be[tid+768], 0.f);
}

// LayerNorm over rows of 256 (final output)
__global__ __launch_bounds__(256) void ln_out_kernel(
        const float* __restrict__ X, const float* __restrict__ g,
        const float* __restrict__ be, float* __restrict__ Y) {
    int b = blockIdx.x, tid = threadIdx.x;
    __shared__ float2 red[4];
    float v0 = X[(size_t)b*256 + tid];
    float2 v = make_float2(v0, v0*v0);
    int lane = tid & 63, wave = tid >> 6;
    for (int off = 32; off; off >>= 1) { v.x += __shfl_down(v.x, off); v.y += __shfl_down(v.y, off); }
    if (lane == 0) red[wave] = v;
    __syncthreads();
    float s = 0.f, s2 = 0.f;
    #pragma unroll
    for (int wv = 0; wv < 4; ++wv) { s += red[wv].x; s2 += red[wv].y; }
    float mu  = s  * (1.f/256.f);
    float var = s2 * (1.f/256.f) - mu*mu;
    Y[(size_t)b*256 + tid] = (v0 - mu) * rsqrtf(var + EPS) * g[tid] + be[tid];
}

// ---------------------------------------------------------------------------
extern "C" void kernel_launch(void* const* d_in, const int* in_sizes, int n_in,
                              void* d_out, int out_size, void* d_ws, size_t ws_size,
                              hipStream_t stream) {
    const float* x    = (const float*)d_in[0];
    const float* qWe0 = (const float*)d_in[1];
    const float* qbe0 = (const float*)d_in[2];
    const float* qgi0 = (const float*)d_in[3];
    const float* qbi0 = (const float*)d_in[4];
    const float* rot0 = (const float*)d_in[5];
    const float* ent0 = (const float*)d_in[6];
    const float* qWd0 = (const float*)d_in[7];
    const float* qbd0 = (const float*)d_in[8];
    const float* qgo0 = (const float*)d_in[9];
    const float* qbo0 = (const float*)d_in[10];
    const float* qWe1 = (const float*)d_in[11];
    const float* qbe1 = (const float*)d_in[12];
    const float* qgi1 = (const float*)d_in[13];
    const float* qbi1 = (const float*)d_in[14];
    const float* rot1 = (const float*)d_in[15];
    const float* ent1 = (const float*)d_in[16];
    const float* qWd1 = (const float*)d_in[17];
    const float* qbd1 = (const float*)d_in[18];
    const float* qgo1 = (const float*)d_in[19];
    const float* qbo1 = (const float*)d_in[20];
    const float* W2   = (const float*)d_in[21];
    const float* b2   = (const float*)d_in[22];
    const float* ln2g = (const float*)d_in[23];
    const float* ln2b = (const float*)d_in[24];
    const float* Wo   = (const float*)d_in[25];
    const float* bo   = (const float*)d_in[26];
    const float* lnog = (const float*)d_in[27];
    const float* lnob = (const float*)d_in[28];
    float* out = (float*)d_out;
    float* ws  = (float*)d_ws;

    // workspace layout (floats)
    float2* Uc = (float2*)ws;            // 288 float2
    float2* Cc = Uc + 288;               // 66 float2  (ends at float 708)
    float* A0  = ws + 1024;              // 512*12
    float* m0  = A0 + 6144;
    float* A1  = m0 + 6144;
    float* m1  = A1 + 6144;              // ends at 25600
    float* h1T = ws + 32768;             // 512*512 (H1 x B, transposed)
    float* h2T = h1T + 262144;           // 512*512
    float* t3  = h2T + 262144;           // 512*1024
    float* t3n = t3 + 524288;            // 512*1024
    float* t4  = t3n + 524288;           // 512*256
    // total 1,736,704 floats ~= 6.95 MB

    hipLaunchKernelGGL(consts_kernel, dim3(1), dim3(256), 0, stream,
                       rot0, ent0, rot1, ent1, Uc, Cc);

    // layer 0
    hipLaunchKernelGGL(encode_kernel, dim3(12), dim3(512), 0, stream,
                       x, 512, 1, qWe0, qbe0, qgi0, qbi0, A0);
    hipLaunchKernelGGL(qsim_kernel, dim3(512), dim3(256), 0, stream,
                       A0, Uc, Cc, 0, m0);
    hipLaunchKernelGGL(decode_kernel, dim3(512), dim3(512), 0, stream,
                       m0, qWd0, qbd0, qgo0, qbo0, h1T);

    // layer 1 (reads transposed h1T)
    hipLaunchKernelGGL(encode_kernel, dim3(12), dim3(512), 0, stream,
                       h1T, 1, 512, qWe1, qbe1, qgi1, qbi1, A1);
    hipLaunchKernelGGL(qsim_kernel, dim3(512), dim3(256), 0, stream,
                       A1, Uc, Cc, 1, m1);
    hipLaunchKernelGGL(decode_kernel, dim3(512), dim3(512), 0, stream,
                       m1, qWd1, qbd1, qgo1, qbo1, h2T);

    // MLP head
    hipLaunchKernelGGL(gemm1_kernel, dim3(8, 32), dim3(256), 0, stream,
                       h2T, W2, b2, t3);
    hipLaunchKernelGGL(ln_relu_kernel, dim3(512), dim3(256), 0, stream,
                       t3, ln2g, ln2b, t3n);
    hipLaunchKernelGGL(gemm2_kernel, dim3(16, 8), dim3(256), 0, stream,
                       t3n, Wo, bo, t4);
    hipLaunchKernelGGL(ln_out_kernel, dim3(512), dim3(256), 0, stream,
                       t4, lnog, lnob, out);
}

// Round 2
// 343.095 us; speedup vs baseline: 1.2634x; 1.2634x over previous
//
#include <hip/hip_runtime.h>
#include <math.h>

#define EPS   1e-5f
#define NQ    12
#define DEPTH 3
#define BATCH 512
#define DIM   4096   // 2^NQ

__device__ inline float2 cmul(float2 a, float2 b) {
    return make_float2(a.x*b.x - a.y*b.y, a.x*b.y + a.y*b.x);
}
__device__ inline float2 cadd(float2 a, float2 b) {
    return make_float2(a.x + b.x, a.y + b.y);
}

// ---------------------------------------------------------------------------
// Precompute U = Rz@Ry@Rx for both layers (2*3*12 matrices, 4 complex each)
// and CRY (cos,sin) pairs (2*3*11).
// ---------------------------------------------------------------------------
__global__ void consts_kernel(const float* __restrict__ rot0, const float* __restrict__ ent0,
                              const float* __restrict__ rot1, const float* __restrict__ ent1,
                              float2* __restrict__ Uc, float2* __restrict__ Cc) {
    int t = threadIdx.x;
    if (t < 72) {
        int layer = t / 36, rem = t % 36, d = rem / 12, q = rem % 12;
        const float* rot = layer ? rot1 : rot0;
        float hx = 0.5f * rot[(d*NQ + q)*3 + 0];
        float hy = 0.5f * rot[(d*NQ + q)*3 + 1];
        float hz = 0.5f * rot[(d*NQ + q)*3 + 2];
        float cx = cosf(hx), sx = sinf(hx);
        float cy = cosf(hy), sy = sinf(hy);
        // M1 = Ry @ Rx
        float2 m00 = make_float2( cy*cx,  sy*sx);
        float2 m01 = make_float2(-sy*cx, -cy*sx);
        float2 m10 = make_float2( sy*cx, -cy*sx);
        float2 m11 = make_float2( cy*cx, -sy*sx);
        float2 ez  = make_float2(cosf(hz), -sinf(hz));   // e^{-i hz}
        float2 ezc = make_float2(ez.x, -ez.y);           // e^{+i hz}
        float2* U = Uc + t*4;   // index = layer*36 + d*12 + q
        U[0] = cmul(ez,  m00);
        U[1] = cmul(ez,  m01);
        U[2] = cmul(ezc, m10);
        U[3] = cmul(ezc, m11);
    } else if (t < 72 + 66) {
        int idx = t - 72, layer = idx / 33, rem = idx % 33;
        const float* ent = layer ? ent1 : ent0;
        float th = 0.5f * ent[rem];
        Cc[idx] = make_float2(cosf(th), sinf(th));
    }
}

// ---------------------------------------------------------------------------
// Encode GEMM, row-major X (B x 512): Yraw[b][q] = X[b,:] . We[q,:] + be[q]
// One wave per batch row; We staged in LDS; grid = B/4 = 128 blocks.
// ---------------------------------------------------------------------------
__global__ __launch_bounds__(256) void encode_rm_kernel(
        const float* __restrict__ X,    // (B, 512) row-major
        const float* __restrict__ We,   // (NQ, 512)
        const float* __restrict__ be,
        float* __restrict__ Yraw) {     // (B, NQ)
    __shared__ float w[NQ][512];
    int tid = threadIdx.x;
    {
        const float4* src = (const float4*)We;
        float4* dst = (float4*)&w[0][0];
        #pragma unroll
        for (int i = tid; i < NQ*512/4; i += 256) dst[i] = src[i];
    }
    __syncthreads();
    int wave = tid >> 6, lane = tid & 63;
    int b = blockIdx.x * 4 + wave;
    const float4* xr = (const float4*)(X + (size_t)b * 512);
    float acc[NQ] = {};
    #pragma unroll
    for (int j = 0; j < 2; ++j) {
        float4 xv = xr[lane + 64*j];
        #pragma unroll
        for (int q = 0; q < NQ; ++q) {
            float4 wv = ((const float4*)&w[q][0])[lane + 64*j];
            acc[q] += xv.x*wv.x + xv.y*wv.y + xv.z*wv.z + xv.w*wv.w;
        }
    }
    #pragma unroll
    for (int q = 0; q < NQ; ++q) {
        float v = acc[q];
        #pragma unroll
        for (int off = 32; off; off >>= 1) v += __shfl_xor(v, off);
        if (lane == q) Yraw[b*NQ + q] = v + be[q];
    }
}

// ---------------------------------------------------------------------------
// Encode GEMM, k-major XT (512k x 512b): Yraw[b][q] = sum_k XT[k][b]*We[q][k]
// Block: 64 batch cols x 4 k-slices; coalesced reads of XT rows. grid = 8.
// ---------------------------------------------------------------------------
__global__ __launch_bounds__(256) void encode_cm_kernel(
        const float* __restrict__ XT,   // (512, 512) k-major
        const float* __restrict__ We,   // (NQ, 512)
        const float* __restrict__ be,
        float* __restrict__ Yraw) {     // (B, NQ)
    __shared__ float w[NQ][512];
    __shared__ float red[4][64][NQ];
    int tid = threadIdx.x;
    {
        const float4* src = (const float4*)We;
        float4* dst = (float4*)&w[0][0];
        #pragma unroll
        for (int i = tid; i < NQ*512/4; i += 256) dst[i] = src[i];
    }
    __syncthreads();
    int r = tid >> 6, c = tid & 63;
    int b = blockIdx.x * 64 + c;
    float acc[NQ] = {};
    for (int k = r; k < 512; k += 4) {
        float xv = XT[(size_t)k*512 + b];
        #pragma unroll
        for (int q = 0; q < NQ; ++q) acc[q] += xv * w[q][k];
    }
    #pragma unroll
    for (int q = 0; q < NQ; ++q) red[r][c][q] = acc[q];
    __syncthreads();
    for (int i = tid; i < 64*NQ; i += 256) {
        int cc = i / NQ, q = i % NQ;
        float v = red[0][cc][q] + red[1][cc][q] + red[2][cc][q] + red[3][cc][q];
        Yraw[(size_t)(blockIdx.x*64 + cc)*NQ + q] = v + be[q];
    }
}

// ---------------------------------------------------------------------------
// Batch-BN (over 512 rows, 12 cols) + tanh. One block of 512 threads.
// ---------------------------------------------------------------------------
__global__ __launch_bounds__(512) void bn_tanh_kernel(
        const float* __restrict__ Yraw, // (512, NQ)
        const float* __restrict__ gi, const float* __restrict__ bi,
        float* __restrict__ A) {        // (512, NQ)
    int b = threadIdx.x;
    float v[NQ];
    #pragma unroll
    for (int q = 0; q < NQ; ++q) v[q] = Yraw[b*NQ + q];
    __shared__ float2 red[NQ][8];
    int lane = b & 63, wave = b >> 6;
    #pragma unroll
    for (int q = 0; q < NQ; ++q) {
        float2 t = make_float2(v[q], v[q]*v[q]);
        for (int off = 32; off; off >>= 1) { t.x += __shfl_down(t.x, off); t.y += __shfl_down(t.y, off); }
        if (lane == 0) red[q][wave] = t;
    }
    __syncthreads();
    #pragma unroll
    for (int q = 0; q < NQ; ++q) {
        float s = 0.f, s2 = 0.f;
        #pragma unroll
        for (int wv = 0; wv < 8; ++wv) { s += red[q][wv].x; s2 += red[q][wv].y; }
        float mu  = s  * (1.f/512.f);
        float var = s2 * (1.f/512.f) - mu*mu;
        A[b*NQ + q] = tanhf((v[q] - mu) * rsqrtf(var + EPS) * gi[q] + bi[q]);
    }
}

// ---------------------------------------------------------------------------
// Quantum sim: one block per sample, state in LDS. Product-state init fused
// with depth-0 single-qubit rotations; then CRY chain + (depth 1,2) gates.
// ---------------------------------------------------------------------------
__global__ __launch_bounds__(256) void qsim_kernel(
        const float* __restrict__ A, const float2* __restrict__ UcAll,
        const float2* __restrict__ CcAll, int layer, float* __restrict__ mout) {
    int b = blockIdx.x, tid = threadIdx.x;
    const float2* Uc = UcAll + layer * DEPTH * NQ * 4;
    const float2* Cc = CcAll + layer * DEPTH * (NQ - 1);
    __shared__ float2 s[DIM];
    __shared__ float red[NQ * 4];

    // --- per-qubit init vectors (encode RY fused with depth-0 rotation U) ---
    float av[NQ]; float n2 = 0.f;
    #pragma unroll
    for (int q = 0; q < NQ; ++q) { av[q] = A[b*NQ + q]; n2 += av[q]*av[q]; }
    float scn = (n2 > 0.f) ? rsqrtf(n2) : 1.f;
    float2 v0[NQ], v1[NQ];
    #pragma unroll
    for (int q = 0; q < NQ; ++q) {
        float a  = av[q] * scn;
        float si = fminf(fabsf(a), 1.f);
        float c  = sqrtf(fmaxf(1.f - si*si, 0.f));
        float ss = (a < 0.f) ? -si : si;
        const float2* U = Uc + q*4;   // d = 0
        v0[q] = make_float2(U[0].x*c + U[1].x*ss, U[0].y*c + U[1].y*ss);
        v1[q] = make_float2(U[2].x*c + U[3].x*ss, U[2].y*c + U[3].y*ss);
    }
    // --- product-state init: amp[i] = prod_q (bit_q(i) ? v1 : v0) ---
    int hi = tid * 16;
    float2 common = make_float2(1.f, 0.f);
    #pragma unroll
    for (int q = 0; q < 8; ++q)
        common = cmul(common, ((hi >> (11 - q)) & 1) ? v1[q] : v0[q]);
    #pragma unroll
    for (int k = 0; k < 16; ++k) {
        float2 amp = common;
        #pragma unroll
        for (int q = 8; q < NQ; ++q)
            amp = cmul(amp, ((k >> (11 - q)) & 1) ? v1[q] : v0[q]);
        s[hi + k] = amp;
    }
    __syncthreads();

    for (int d = 0; d < DEPTH; ++d) {
        if (d > 0) {
            for (int q = 0; q < NQ; ++q) {
                const float2 u00 = Uc[(d*NQ+q)*4+0], u01 = Uc[(d*NQ+q)*4+1];
                const float2 u10 = Uc[(d*NQ+q)*4+2], u11 = Uc[(d*NQ+q)*4+3];
                int shift = 11 - q, st = 1 << shift;
                #pragma unroll
                for (int pp = 0; pp < 8; ++pp) {
                    int p  = tid + pp*256;
                    int i0 = ((p >> shift) << (shift + 1)) | (p & (st - 1));
                    int i1 = i0 | st;
                    float2 a0 = s[i0], a1 = s[i1];
                    s[i0] = cadd(cmul(u00, a0), cmul(u01, a1));
                    s[i1] = cadd(cmul(u10, a0), cmul(u11, a1));
                }
                __syncthreads();
            }
        }
        for (int i = 0; i < NQ - 1; ++i) {
            float2 cs_ = Cc[d*(NQ-1) + i];
            float co = cs_.x, si = cs_.y;
            int tshift = 10 - i;
            int lowmask = (1 << tshift) - 1;
            #pragma unroll
            for (int pp = 0; pp < 4; ++pp) {
                int p  = tid + pp*256;
                int i0 = ((p >> tshift) << (tshift + 2)) | (1 << (tshift + 1)) | (p & lowmask);
                int i1 = i0 | (1 << tshift);
                float2 a0 = s[i0], a1 = s[i1];
                s[i0] = make_float2(co*a0.x - si*a1.x, co*a0.y - si*a1.y);
                s[i1] = make_float2(si*a0.x + co*a1.x, si*a0.y + co*a1.y);
            }
            __syncthreads();
        }
    }

    // --- measurement: P(qubit q == 1) ---
    float msum = 0.f, p8 = 0.f, p9 = 0.f, p10 = 0.f, p11 = 0.f;
    #pragma unroll
    for (int k = 0; k < 16; ++k) {
        float2 a = s[hi + k];
        float mag = a.x*a.x + a.y*a.y;
        msum += mag;
        if (k & 8) p8  += mag;
        if (k & 4) p9  += mag;
        if (k & 2) p10 += mag;
        if (k & 1) p11 += mag;
    }
    float pq[NQ];
    #pragma unroll
    for (int q = 0; q < 8; ++q) pq[q] = ((tid >> (7 - q)) & 1) ? msum : 0.f;
    pq[8] = p8; pq[9] = p9; pq[10] = p10; pq[11] = p11;
    int lane = tid & 63, wave = tid >> 6;
    #pragma unroll
    for (int q = 0; q < NQ; ++q) {
        float v = pq[q];
        for (int off = 32; off; off >>= 1) v += __shfl_down(v, off);
        if (lane == 0) red[q*4 + wave] = v;
    }
    __syncthreads();
    if (tid < NQ)
        mout[b*NQ + tid] = red[tid*4] + red[tid*4+1] + red[tid*4+2] + red[tid*4+3];
}

// ---------------------------------------------------------------------------
// Decode: Z[:,h] = m @ Wd[h] + bd[h]; BN over batch (block == column h);
// write TRANSPOSED (H x B) so next layer's reads/writes coalesce.
// ---------------------------------------------------------------------------
__global__ __launch_bounds__(512) void decode_kernel(
        const float* __restrict__ m, const float* __restrict__ Wd,
        const float* __restrict__ bd, const float* __restrict__ go,
        const float* __restrict__ bo, float* __restrict__ outT) {
    int h = blockIdx.x, b = threadIdx.x;
    __shared__ float sm[BATCH * NQ];
    __shared__ float2 red[8];
    for (int idx = b; idx < BATCH * NQ; idx += 512) sm[idx] = m[idx];
    __syncthreads();
    float z = bd[h];
    #pragma unroll
    for (int q = 0; q < NQ; ++q) z += sm[b*NQ + q] * Wd[h*NQ + q];

    float2 v = make_float2(z, z*z);
    int lane = b & 63, wave = b >> 6;
    for (int off = 32; off; off >>= 1) { v.x += __shfl_down(v.x, off); v.y += __shfl_down(v.y, off); }
    if (lane == 0) red[wave] = v;
    __syncthreads();
    float s = 0.f, s2 = 0.f;
    #pragma unroll
    for (int wv = 0; wv < 8; ++wv) { s += red[wv].x; s2 += red[wv].y; }
    float mu  = s  * (1.f/512.f);
    float var = s2 * (1.f/512.f) - mu*mu;
    outT[(size_t)h*BATCH + b] = (z - mu) * rsqrtf(var + EPS) * go[h] + bo[h];
}

// ---------------------------------------------------------------------------
// SGEMM 1: C(512x1024) = A^T-stored(512k x 512b) x W2(1024x512)^T + b2
// Tile BM=64, BN=32, BK=32. grid (8, 32).
// ---------------------------------------------------------------------------
__global__ __launch_bounds__(256) void gemm1_kernel(
        const float* __restrict__ AT,   // (K=512, B=512), k-major
        const float* __restrict__ W,    // (N=1024, K=512)
        const float* __restrict__ bias,
        float* __restrict__ Cmat) {     // (512, 1024)
    __shared__ float As[32][64];
    __shared__ float Bs[32][33];
    int b0 = blockIdx.x * 64, j0 = blockIdx.y * 32;
    int tid = threadIdx.x;
    int tr = tid >> 4, tc = tid & 15;
    float acc[4][2] = {};
    for (int k0 = 0; k0 < 512; k0 += 32) {
        #pragma unroll
        for (int l = 0; l < 2; ++l) {
            int idx = tid + l*256;                 // [0,512) float4 slots
            int kk = idx >> 4, f4 = idx & 15;
            float4 vv = *(const float4*)(AT + (size_t)(k0 + kk)*512 + b0 + f4*4);
            *(float4*)(&As[kk][f4*4]) = vv;
        }
        {
            int jj = tid >> 3, kkb = (tid & 7) * 4;
            float4 vv = *(const float4*)(W + (size_t)(j0 + jj)*512 + k0 + kkb);
            Bs[kkb+0][jj] = vv.x; Bs[kkb+1][jj] = vv.y;
            Bs[kkb+2][jj] = vv.z; Bs[kkb+3][jj] = vv.w;
        }
        __syncthreads();
        #pragma unroll
        for (int kk = 0; kk < 32; ++kk) {
            float a0 = As[kk][tr*4+0], a1 = As[kk][tr*4+1];
            float a2 = As[kk][tr*4+2], a3 = As[kk][tr*4+3];
            float bb0 = Bs[kk][tc*2+0], bb1 = Bs[kk][tc*2+1];
            acc[0][0] += a0*bb0; acc[0][1] += a0*bb1;
            acc[1][0] += a1*bb0; acc[1][1] += a1*bb1;
            acc[2][0] += a2*bb0; acc[2][1] += a2*bb1;
            acc[3][0] += a3*bb0; acc[3][1] += a3*bb1;
        }
        __syncthreads();
    }
    float2 bia = *(const float2*)(bias + j0 + tc*2);
    #pragma unroll
    for (int r = 0; r < 4; ++r) {
        int bb = b0 + tr*4 + r;
        float2 o = make_float2(acc[r][0] + bia.x, acc[r][1] + bia.y);
        *(float2*)(Cmat + (size_t)bb*1024 + j0 + tc*2) = o;
    }
}

// ---------------------------------------------------------------------------
// SGEMM 2: C(512x256) = A(512x1024) x Wo(256x1024)^T + bo
// Tile BM=32, BN=32, BK=32. grid (16, 8).
// ---------------------------------------------------------------------------
__global__ __launch_bounds__(256) void gemm2_kernel(
        const float* __restrict__ Amat, // (512, 1024) row-major
        const float* __restrict__ W,    // (256, 1024)
        const float* __restrict__ bias,
        float* __restrict__ Cmat) {     // (512, 256)
    __shared__ float As[32][33];
    __shared__ float Bs[32][33];
    int b0 = blockIdx.x * 32, j0 = blockIdx.y * 32;
    int tid = threadIdx.x;
    int tr = tid >> 4, tc = tid & 15;
    float acc[2][2] = {};
    for (int k0 = 0; k0 < 1024; k0 += 32) {
        {
            int rr = tid >> 3, kkb = (tid & 7) * 4;
            float4 av = *(const float4*)(Amat + (size_t)(b0 + rr)*1024 + k0 + kkb);
            As[kkb+0][rr] = av.x; As[kkb+1][rr] = av.y;
            As[kkb+2][rr] = av.z; As[kkb+3][rr] = av.w;
            float4 wv = *(const float4*)(W + (size_t)(j0 + rr)*1024 + k0 + kkb);
            Bs[kkb+0][rr] = wv.x; Bs[kkb+1][rr] = wv.y;
            Bs[kkb+2][rr] = wv.z; Bs[kkb+3][rr] = wv.w;
        }
        __syncthreads();
        #pragma unroll
        for (int kk = 0; kk < 32; ++kk) {
            float a0 = As[kk][tr*2+0], a1 = As[kk][tr*2+1];
            float bb0 = Bs[kk][tc*2+0], bb1 = Bs[kk][tc*2+1];
            acc[0][0] += a0*bb0; acc[0][1] += a0*bb1;
            acc[1][0] += a1*bb0; acc[1][1] += a1*bb1;
        }
        __syncthreads();
    }
    float2 bia = *(const float2*)(bias + j0 + tc*2);
    #pragma unroll
    for (int r = 0; r < 2; ++r) {
        int bb = b0 + tr*2 + r;
        float2 o = make_float2(acc[r][0] + bia.x, acc[r][1] + bia.y);
        *(float2*)(Cmat + (size_t)bb*256 + j0 + tc*2) = o;
    }
}

// ---------------------------------------------------------------------------
// LayerNorm (+ReLU) over rows of 1024
// ---------------------------------------------------------------------------
__global__ __launch_bounds__(256) void ln_relu_kernel(
        const float* __restrict__ X, const float* __restrict__ g,
        const float* __restrict__ be, float* __restrict__ Y) {
    int b = blockIdx.x, tid = threadIdx.x;
    __shared__ float2 red[4];
    const float* xr = X + (size_t)b * 1024;
    float v0 = xr[tid], v1 = xr[tid+256], v2 = xr[tid+512], v3 = xr[tid+768];
    float2 v = make_float2(v0+v1+v2+v3, v0*v0+v1*v1+v2*v2+v3*v3);
    int lane = tid & 63, wave = tid >> 6;
    for (int off = 32; off; off >>= 1) { v.x += __shfl_down(v.x, off); v.y += __shfl_down(v.y, off); }
    if (lane == 0) red[wave] = v;
    __syncthreads();
    float s = 0.f, s2 = 0.f;
    #pragma unroll
    for (int wv = 0; wv < 4; ++wv) { s += red[wv].x; s2 += red[wv].y; }
    float mu  = s  * (1.f/1024.f);
    float var = s2 * (1.f/1024.f) - mu*mu;
    float inv = rsqrtf(var + EPS);
    float* yr = Y + (size_t)b * 1024;
    yr[tid]     = fmaxf((v0-mu)*inv*g[tid]     + be[tid],     0.f);
    yr[tid+256] = fmaxf((v1-mu)*inv*g[tid+256] + be[tid+256], 0.f);
    yr[tid+512] = fmaxf((v2-mu)*inv*g[tid+512] + be[tid+512], 0.f);
    yr[tid+768] = fmaxf((v3-mu)*inv*g[tid+768] + be[tid+768], 0.f);
}

// LayerNorm over rows of 256 (final output)
__global__ __launch_bounds__(256) void ln_out_kernel(
        const float* __restrict__ X, const float* __restrict__ g,
        const float* __restrict__ be, float* __restrict__ Y) {
    int b = blockIdx.x, tid = threadIdx.x;
    __shared__ float2 red[4];
    float v0 = X[(size_t)b*256 + tid];
    float2 v = make_float2(v0, v0*v0);
    int lane = tid & 63, wave = tid >> 6;
    for (int off = 32; off; off >>= 1) { v.x += __shfl_down(v.x, off); v.y += __shfl_down(v.y, off); }
    if (lane == 0) red[wave] = v;
    __syncthreads();
    float s = 0.f, s2 = 0.f;
    #pragma unroll
    for (int wv = 0; wv < 4; ++wv) { s += red[wv].x; s2 += red[wv].y; }
    float mu  = s  * (1.f/256.f);
    float var = s2 * (1.f/256.f) - mu*mu;
    Y[(size_t)b*256 + tid] = (v0 - mu) * rsqrtf(var + EPS) * g[tid] + be[tid];
}

// ---------------------------------------------------------------------------
extern "C" void kernel_launch(void* const* d_in, const int* in_sizes, int n_in,
                              void* d_out, int out_size, void* d_ws, size_t ws_size,
                              hipStream_t stream) {
    const float* x    = (const float*)d_in[0];
    const float* qWe0 = (const float*)d_in[1];
    const float* qbe0 = (const float*)d_in[2];
    const float* qgi0 = (const float*)d_in[3];
    const float* qbi0 = (const float*)d_in[4];
    const float* rot0 = (const float*)d_in[5];
    const float* ent0 = (const float*)d_in[6];
    const float* qWd0 = (const float*)d_in[7];
    const float* qbd0 = (const float*)d_in[8];
    const float* qgo0 = (const float*)d_in[9];
    const float* qbo0 = (const float*)d_in[10];
    const float* qWe1 = (const float*)d_in[11];
    const float* qbe1 = (const float*)d_in[12];
    const float* qgi1 = (const float*)d_in[13];
    const float* qbi1 = (const float*)d_in[14];
    const float* rot1 = (const float*)d_in[15];
    const float* ent1 = (const float*)d_in[16];
    const float* qWd1 = (const float*)d_in[17];
    const float* qbd1 = (const float*)d_in[18];
    const float* qgo1 = (const float*)d_in[19];
    const float* qbo1 = (const float*)d_in[20];
    const float* W2   = (const float*)d_in[21];
    const float* b2   = (const float*)d_in[22];
    const float* ln2g = (const float*)d_in[23];
    const float* ln2b = (const float*)d_in[24];
    const float* Wo   = (const float*)d_in[25];
    const float* bo   = (const float*)d_in[26];
    const float* lnog = (const float*)d_in[27];
    const float* lnob = (const float*)d_in[28];
    float* out = (float*)d_out;
    float* ws  = (float*)d_ws;

    // workspace layout (floats)
    float2* Uc = (float2*)ws;            // 288 float2
    float2* Cc = Uc + 288;               // 66 float2  (ends at float 708)
    float* A0  = ws + 1024;              // 512*12
    float* m0  = A0 + 6144;
    float* A1  = m0 + 6144;
    float* m1  = A1 + 6144;              // ends at 25600
    float* Yraw = ws + 25600;            // 512*12 (reused by both layers)
    float* h1T = ws + 32768;             // 512*512 (H1 x B, transposed)
    float* h2T = h1T + 262144;           // 512*512
    float* t3  = h2T + 262144;           // 512*1024
    float* t3n = t3 + 524288;            // 512*1024
    float* t4  = t3n + 524288;           // 512*256
    // total ~6.95 MB

    hipLaunchKernelGGL(consts_kernel, dim3(1), dim3(256), 0, stream,
                       rot0, ent0, rot1, ent1, Uc, Cc);

    // layer 0
    hipLaunchKernelGGL(encode_rm_kernel, dim3(128), dim3(256), 0, stream,
                       x, qWe0, qbe0, Yraw);
    hipLaunchKernelGGL(bn_tanh_kernel, dim3(1), dim3(512), 0, stream,
                       Yraw, qgi0, qbi0, A0);
    hipLaunchKernelGGL(qsim_kernel, dim3(512), dim3(256), 0, stream,
                       A0, Uc, Cc, 0, m0);
    hipLaunchKernelGGL(decode_kernel, dim3(512), dim3(512), 0, stream,
                       m0, qWd0, qbd0, qgo0, qbo0, h1T);

    // layer 1 (reads k-major h1T with coalesced rows)
    hipLaunchKernelGGL(encode_cm_kernel, dim3(8), dim3(256), 0, stream,
                       h1T, qWe1, qbe1, Yraw);
    hipLaunchKernelGGL(bn_tanh_kernel, dim3(1), dim3(512), 0, stream,
                       Yraw, qgi1, qbi1, A1);
    hipLaunchKernelGGL(qsim_kernel, dim3(512), dim3(256), 0, stream,
                       A1, Uc, Cc, 1, m1);
    hipLaunchKernelGGL(decode_kernel, dim3(512), dim3(512), 0, stream,
                       m1, qWd1, qbd1, qgo1, qbo1, h2T);

    // MLP head
    hipLaunchKernelGGL(gemm1_kernel, dim3(8, 32), dim3(256), 0, stream,
                       h2T, W2, b2, t3);
    hipLaunchKernelGGL(ln_relu_kernel, dim3(512), dim3(256), 0, stream,
                       t3, ln2g, ln2b, t3n);
    hipLaunchKernelGGL(gemm2_kernel, dim3(16, 8), dim3(256), 0, stream,
                       t3n, Wo, bo, t4);
    hipLaunchKernelGGL(ln_out_kernel, dim3(512), dim3(256), 0, stream,
                       t4, lnog, lnob, out);
}

// Round 3
// 326.571 us; speedup vs baseline: 1.3274x; 1.0506x over previous
//
#include <hip/hip_runtime.h>
#include <math.h>

#define EPS   1e-5f
#define NQ    12
#define DEPTH 3
#define BATCH 512
#define DIM   4096   // 2^NQ

__device__ inline float2 cmul(float2 a, float2 b) {
    return make_float2(a.x*b.x - a.y*b.y, a.x*b.y + a.y*b.x);
}
// ua*s + ub*p (complex)
__device__ inline float2 cmac2(float2 ua, float2 s, float2 ub, float2 p) {
    return make_float2(ua.x*s.x - ua.y*s.y + ub.x*p.x - ub.y*p.y,
                       ua.x*s.y + ua.y*s.x + ub.x*p.y + ub.y*p.x);
}
// real rotation: co*a + s2*p (componentwise)
__device__ inline float2 rot2(float co, float s2, float2 a, float2 p) {
    return make_float2(co*a.x + s2*p.x, co*a.y + s2*p.y);
}

// ---------------------------------------------------------------------------
// Precompute U = Rz@Ry@Rx for both layers (2*3*12 matrices, 4 complex each)
// and CRY (cos,sin) pairs (2*3*11).
// ---------------------------------------------------------------------------
__global__ void consts_kernel(const float* __restrict__ rot0, const float* __restrict__ ent0,
                              const float* __restrict__ rot1, const float* __restrict__ ent1,
                              float2* __restrict__ Uc, float2* __restrict__ Cc) {
    int t = threadIdx.x;
    if (t < 72) {
        int layer = t / 36, rem = t % 36, d = rem / 12, q = rem % 12;
        const float* rot = layer ? rot1 : rot0;
        float hx = 0.5f * rot[(d*NQ + q)*3 + 0];
        float hy = 0.5f * rot[(d*NQ + q)*3 + 1];
        float hz = 0.5f * rot[(d*NQ + q)*3 + 2];
        float cx = cosf(hx), sx = sinf(hx);
        float cy = cosf(hy), sy = sinf(hy);
        // M1 = Ry @ Rx
        float2 m00 = make_float2( cy*cx,  sy*sx);
        float2 m01 = make_float2(-sy*cx, -cy*sx);
        float2 m10 = make_float2( sy*cx, -cy*sx);
        float2 m11 = make_float2( cy*cx, -sy*sx);
        float2 ez  = make_float2(cosf(hz), -sinf(hz));   // e^{-i hz}
        float2 ezc = make_float2(ez.x, -ez.y);           // e^{+i hz}
        float2* U = Uc + t*4;   // index = layer*36 + d*12 + q
        U[0] = cmul(ez,  m00);
        U[1] = cmul(ez,  m01);
        U[2] = cmul(ezc, m10);
        U[3] = cmul(ezc, m11);
    } else if (t < 72 + 66) {
        int idx = t - 72, layer = idx / 33, rem = idx % 33;
        const float* ent = layer ? ent1 : ent0;
        float th = 0.5f * ent[rem];
        Cc[idx] = make_float2(cosf(th), sinf(th));
    }
}

// ---------------------------------------------------------------------------
// Encode GEMM, row-major X (B x 512): Yraw[b][q] = X[b,:] . We[q,:] + be[q]
// One wave per batch row; We staged in LDS; grid = B/4 = 128 blocks.
// ---------------------------------------------------------------------------
__global__ __launch_bounds__(256) void encode_rm_kernel(
        const float* __restrict__ X,    // (B, 512) row-major
        const float* __restrict__ We,   // (NQ, 512)
        const float* __restrict__ be,
        float* __restrict__ Yraw) {     // (B, NQ)
    __shared__ float w[NQ][512];
    int tid = threadIdx.x;
    {
        const float4* src = (const float4*)We;
        float4* dst = (float4*)&w[0][0];
        #pragma unroll
        for (int i = tid; i < NQ*512/4; i += 256) dst[i] = src[i];
    }
    __syncthreads();
    int wave = tid >> 6, lane = tid & 63;
    int b = blockIdx.x * 4 + wave;
    const float4* xr = (const float4*)(X + (size_t)b * 512);
    float acc[NQ] = {};
    #pragma unroll
    for (int j = 0; j < 2; ++j) {
        float4 xv = xr[lane + 64*j];
        #pragma unroll
        for (int q = 0; q < NQ; ++q) {
            float4 wv = ((const float4*)&w[q][0])[lane + 64*j];
            acc[q] += xv.x*wv.x + xv.y*wv.y + xv.z*wv.z + xv.w*wv.w;
        }
    }
    #pragma unroll
    for (int q = 0; q < NQ; ++q) {
        float v = acc[q];
        #pragma unroll
        for (int off = 32; off; off >>= 1) v += __shfl_xor(v, off);
        if (lane == q) Yraw[b*NQ + q] = v + be[q];
    }
}

// ---------------------------------------------------------------------------
// Encode GEMM, k-major XT (512k x 512b): Yraw[b][q] = sum_k XT[k][b]*We[q][k]
// Block: 64 batch cols x 4 k-slices; coalesced reads of XT rows. grid = 8.
// ---------------------------------------------------------------------------
__global__ __launch_bounds__(256) void encode_cm_kernel(
        const float* __restrict__ XT,   // (512, 512) k-major
        const float* __restrict__ We,   // (NQ, 512)
        const float* __restrict__ be,
        float* __restrict__ Yraw) {     // (B, NQ)
    __shared__ float w[NQ][512];
    __shared__ float red[4][64][NQ];
    int tid = threadIdx.x;
    {
        const float4* src = (const float4*)We;
        float4* dst = (float4*)&w[0][0];
        #pragma unroll
        for (int i = tid; i < NQ*512/4; i += 256) dst[i] = src[i];
    }
    __syncthreads();
    int r = tid >> 6, c = tid & 63;
    int b = blockIdx.x * 64 + c;
    float acc[NQ] = {};
    for (int k = r; k < 512; k += 4) {
        float xv = XT[(size_t)k*512 + b];
        #pragma unroll
        for (int q = 0; q < NQ; ++q) acc[q] += xv * w[q][k];
    }
    #pragma unroll
    for (int q = 0; q < NQ; ++q) red[r][c][q] = acc[q];
    __syncthreads();
    for (int i = tid; i < 64*NQ; i += 256) {
        int cc = i / NQ, q = i % NQ;
        float v = red[0][cc][q] + red[1][cc][q] + red[2][cc][q] + red[3][cc][q];
        Yraw[(size_t)(blockIdx.x*64 + cc)*NQ + q] = v + be[q];
    }
}

// ---------------------------------------------------------------------------
// Batch-BN (over 512 rows, 12 cols) + tanh. One block of 512 threads.
// ---------------------------------------------------------------------------
__global__ __launch_bounds__(512) void bn_tanh_kernel(
        const float* __restrict__ Yraw, // (512, NQ)
        const float* __restrict__ gi, const float* __restrict__ bi,
        float* __restrict__ A) {        // (512, NQ)
    int b = threadIdx.x;
    float v[NQ];
    #pragma unroll
    for (int q = 0; q < NQ; ++q) v[q] = Yraw[b*NQ + q];
    __shared__ float2 red[NQ][8];
    int lane = b & 63, wave = b >> 6;
    #pragma unroll
    for (int q = 0; q < NQ; ++q) {
        float2 t = make_float2(v[q], v[q]*v[q]);
        for (int off = 32; off; off >>= 1) { t.x += __shfl_down(t.x, off); t.y += __shfl_down(t.y, off); }
        if (lane == 0) red[q][wave] = t;
    }
    __syncthreads();
    #pragma unroll
    for (int q = 0; q < NQ; ++q) {
        float s = 0.f, s2 = 0.f;
        #pragma unroll
        for (int wv = 0; wv < 8; ++wv) { s += red[q][wv].x; s2 += red[q][wv].y; }
        float mu  = s  * (1.f/512.f);
        float var = s2 * (1.f/512.f) - mu*mu;
        A[b*NQ + q] = tanhf((v[q] - mu) * rsqrtf(var + EPS) * gi[q] + bi[q]);
    }
}

// ---------------------------------------------------------------------------
// Quantum sim, register-resident state: 256 threads/sample, 16 float2
// amps/thread. amp index = tid*16 + k. Qubit q <-> amp bit (11-q):
//   q=8..11 -> k bits 3..0  (in-register pairs)
//   q=2..7  -> lane bits 5..0 (shfl_xor)
//   q=0..1  -> wave bits 1..0 (LDS exchange, 7 instances total)
// Encode RY + depth-0 rotations fused into product-state init.
// ---------------------------------------------------------------------------
__global__ __launch_bounds__(256) void qsim_kernel(
        const float* __restrict__ A, const float2* __restrict__ UcAll,
        const float2* __restrict__ CcAll, int layer, float* __restrict__ mout) {
    int b = blockIdx.x, tid = threadIdx.x;
    const float2* Uc = UcAll + layer * DEPTH * NQ * 4;
    const float2* Cc = CcAll + layer * DEPTH * (NQ - 1);
    __shared__ float2 lds2[DIM];      // transposed exchange buffer: [k*256 + tid]
    __shared__ float red[NQ][4];

    // --- per-qubit init vectors (encode RY fused with depth-0 rotation U) ---
    float av[NQ]; float n2 = 0.f;
    #pragma unroll
    for (int q = 0; q < NQ; ++q) { av[q] = A[b*NQ + q]; n2 += av[q]*av[q]; }
    float scn = (n2 > 0.f) ? rsqrtf(n2) : 1.f;
    float2 v0[NQ], v1[NQ];
    #pragma unroll
    for (int q = 0; q < NQ; ++q) {
        float a  = av[q] * scn;
        float sv = fminf(fabsf(a), 1.f);
        float c  = sqrtf(fmaxf(1.f - sv*sv, 0.f));
        float ss = (a < 0.f) ? -sv : sv;
        const float2* U = Uc + q*4;   // d = 0
        v0[q] = make_float2(U[0].x*c + U[1].x*ss, U[0].y*c + U[1].y*ss);
        v1[q] = make_float2(U[2].x*c + U[3].x*ss, U[2].y*c + U[3].y*ss);
    }
    // common factor over qubits 0..7 (tid bits 7..0)
    float2 common = make_float2(1.f, 0.f);
    #pragma unroll
    for (int q = 0; q < 8; ++q)
        common = cmul(common, ((tid >> (7-q)) & 1) ? v1[q] : v0[q]);
    // tensor build over k bits (qubits 11..8 = bits 0..3)
    float2 amp[16];
    amp[0] = common;
    #pragma unroll
    for (int m = 0; m < 4; ++m) {
        const int q = 11 - m;
        #pragma unroll
        for (int k = 0; k < (1<<m); ++k) {
            amp[k | (1<<m)] = cmul(amp[k], v1[q]);
            amp[k]          = cmul(amp[k], v0[q]);
        }
    }

    for (int d = 0; d < DEPTH; ++d) {
        if (d > 0) {
            #pragma unroll
            for (int q = 0; q < NQ; ++q) {
                const float2 u00 = Uc[(d*NQ+q)*4+0], u01 = Uc[(d*NQ+q)*4+1];
                const float2 u10 = Uc[(d*NQ+q)*4+2], u11 = Uc[(d*NQ+q)*4+3];
                if (q >= 8) {                       // in-register pairs
                    const int bp = 11 - q;          // 0..3
                    #pragma unroll
                    for (int g = 0; g < 8; ++g) {
                        const int j0 = ((g >> bp) << (bp+1)) | (g & ((1<<bp)-1));
                        const int j1 = j0 | (1<<bp);
                        float2 a0 = amp[j0], a1 = amp[j1];
                        amp[j0] = cmac2(u00, a0, u01, a1);
                        amp[j1] = cmac2(u10, a0, u11, a1);
                    }
                } else if (q >= 2) {                // lane-bit: shfl_xor
                    const int lb = 7 - q;           // 0..5
                    const int mk = 1 << lb;
                    bool myb = (tid >> lb) & 1;
                    float2 ua = myb ? u11 : u00;    // coeff on self
                    float2 ub = myb ? u10 : u01;    // coeff on partner
                    #pragma unroll
                    for (int k = 0; k < 16; ++k) {
                        float2 p;
                        p.x = __shfl_xor(amp[k].x, mk);
                        p.y = __shfl_xor(amp[k].y, mk);
                        amp[k] = cmac2(ua, amp[k], ub, p);
                    }
                } else {                            // wave-bit: LDS exchange
                    const int mk = (q == 0) ? 128 : 64;
                    bool myb = (tid & mk) != 0;
                    float2 ua = myb ? u11 : u00;
                    float2 ub = myb ? u10 : u01;
                    #pragma unroll
                    for (int k = 0; k < 16; ++k) lds2[k*256 + tid] = amp[k];
                    __syncthreads();
                    #pragma unroll
                    for (int k = 0; k < 16; ++k) {
                        float2 p = lds2[k*256 + (tid ^ mk)];
                        amp[k] = cmac2(ua, amp[k], ub, p);
                    }
                    __syncthreads();
                }
            }
        }
        // CRY chain: control i (amp bit 11-i), target i+1 (amp bit 10-i)
        #pragma unroll
        for (int i = 0; i < NQ-1; ++i) {
            float2 cs_ = Cc[d*(NQ-1)+i];
            const float co = cs_.x, si = cs_.y;
            if (i == 0) {                           // ctrl wave b1, tgt wave b0: LDS
                bool ctrl = (tid >> 7) & 1;
                bool t    = (tid >> 6) & 1;
                float co2 = ctrl ? co : 1.f;
                float s2  = ctrl ? (t ? si : -si) : 0.f;
                #pragma unroll
                for (int k = 0; k < 16; ++k) lds2[k*256 + tid] = amp[k];
                __syncthreads();
                #pragma unroll
                for (int k = 0; k < 16; ++k) {
                    float2 p = lds2[k*256 + (tid ^ 64)];
                    amp[k] = rot2(co2, s2, amp[k], p);
                }
                __syncthreads();
            } else if (i <= 6) {                    // tgt lane bit (6-i): shfl
                bool ctrl = (tid >> (7-i)) & 1;
                bool t    = (tid >> (6-i)) & 1;
                const int mk = 1 << (6-i);
                float co2 = ctrl ? co : 1.f;
                float s2  = ctrl ? (t ? si : -si) : 0.f;
                #pragma unroll
                for (int k = 0; k < 16; ++k) {
                    float2 p;
                    p.x = __shfl_xor(amp[k].x, mk);
                    p.y = __shfl_xor(amp[k].y, mk);
                    amp[k] = rot2(co2, s2, amp[k], p);
                }
            } else if (i == 7) {                    // ctrl lane b0, tgt k bit3
                bool ctrl = tid & 1;
                float co2 = ctrl ? co : 1.f;
                float s2  = ctrl ? si : 0.f;
                #pragma unroll
                for (int k = 0; k < 8; ++k) {
                    float2 a0 = amp[k], a1 = amp[k|8];
                    amp[k]   = make_float2(co2*a0.x - s2*a1.x, co2*a0.y - s2*a1.y);
                    amp[k|8] = make_float2(s2*a0.x + co2*a1.x, s2*a0.y + co2*a1.y);
                }
            } else {                                // ctrl/tgt both k bits
                const int tb = 10 - i;              // 2,1,0
                #pragma unroll
                for (int g = 0; g < 4; ++g) {
                    const int low = g & ((1<<tb)-1);
                    const int hig = g >> tb;
                    const int j0 = (hig << (tb+2)) | (1 << (tb+1)) | low;
                    const int j1 = j0 | (1<<tb);
                    float2 a0 = amp[j0], a1 = amp[j1];
                    amp[j0] = make_float2(co*a0.x - si*a1.x, co*a0.y - si*a1.y);
                    amp[j1] = make_float2(si*a0.x + co*a1.x, si*a0.y + co*a1.y);
                }
            }
        }
    }

    // --- measurement: P(qubit q == 1) ---
    float msum = 0.f, p8 = 0.f, p9 = 0.f, p10 = 0.f, p11 = 0.f;
    #pragma unroll
    for (int k = 0; k < 16; ++k) {
        float m = amp[k].x*amp[k].x + amp[k].y*amp[k].y;
        msum += m;
        if (k & 8) p8  += m;
        if (k & 4) p9  += m;
        if (k & 2) p10 += m;
        if (k & 1) p11 += m;
    }
    int lane = tid & 63, wave = tid >> 6;
    #pragma unroll
    for (int q = 0; q < NQ; ++q) {
        float v;
        if (q < 8)        v = ((tid >> (7-q)) & 1) ? msum : 0.f;
        else if (q == 8)  v = p8;
        else if (q == 9)  v = p9;
        else if (q == 10) v = p10;
        else              v = p11;
        #pragma unroll
        for (int off = 32; off; off >>= 1) v += __shfl_xor(v, off);
        if (lane == 0) red[q][wave] = v;
    }
    __syncthreads();
    if (tid < NQ)
        mout[b*NQ + tid] = red[tid][0] + red[tid][1] + red[tid][2] + red[tid][3];
}

// ---------------------------------------------------------------------------
// Decode: Z[:,h] = m @ Wd[h] + bd[h]; BN over batch (block == column h);
// write TRANSPOSED (H x B) so next layer's reads/writes coalesce.
// ---------------------------------------------------------------------------
__global__ __launch_bounds__(512) void decode_kernel(
        const float* __restrict__ m, const float* __restrict__ Wd,
        const float* __restrict__ bd, const float* __restrict__ go,
        const float* __restrict__ bo, float* __restrict__ outT) {
    int h = blockIdx.x, b = threadIdx.x;
    __shared__ float sm[BATCH * NQ];
    __shared__ float2 red[8];
    for (int idx = b; idx < BATCH * NQ; idx += 512) sm[idx] = m[idx];
    __syncthreads();
    float z = bd[h];
    #pragma unroll
    for (int q = 0; q < NQ; ++q) z += sm[b*NQ + q] * Wd[h*NQ + q];

    float2 v = make_float2(z, z*z);
    int lane = b & 63, wave = b >> 6;
    for (int off = 32; off; off >>= 1) { v.x += __shfl_down(v.x, off); v.y += __shfl_down(v.y, off); }
    if (lane == 0) red[wave] = v;
    __syncthreads();
    float s = 0.f, s2 = 0.f;
    #pragma unroll
    for (int wv = 0; wv < 8; ++wv) { s += red[wv].x; s2 += red[wv].y; }
    float mu  = s  * (1.f/512.f);
    float var = s2 * (1.f/512.f) - mu*mu;
    outT[(size_t)h*BATCH + b] = (z - mu) * rsqrtf(var + EPS) * go[h] + bo[h];
}

// ---------------------------------------------------------------------------
// SGEMM 1: C(512x1024) = A^T-stored(512k x 512b) x W2(1024x512)^T + b2
// Tile BM=64, BN=32, BK=32. grid (8, 32).
// ---------------------------------------------------------------------------
__global__ __launch_bounds__(256) void gemm1_kernel(
        const float* __restrict__ AT,   // (K=512, B=512), k-major
        const float* __restrict__ W,    // (N=1024, K=512)
        const float* __restrict__ bias,
        float* __restrict__ Cmat) {     // (512, 1024)
    __shared__ float As[32][64];
    __shared__ float Bs[32][33];
    int b0 = blockIdx.x * 64, j0 = blockIdx.y * 32;
    int tid = threadIdx.x;
    int tr = tid >> 4, tc = tid & 15;
    float acc[4][2] = {};
    for (int k0 = 0; k0 < 512; k0 += 32) {
        #pragma unroll
        for (int l = 0; l < 2; ++l) {
            int idx = tid + l*256;                 // [0,512) float4 slots
            int kk = idx >> 4, f4 = idx & 15;
            float4 vv = *(const float4*)(AT + (size_t)(k0 + kk)*512 + b0 + f4*4);
            *(float4*)(&As[kk][f4*4]) = vv;
        }
        {
            int jj = tid >> 3, kkb = (tid & 7) * 4;
            float4 vv = *(const float4*)(W + (size_t)(j0 + jj)*512 + k0 + kkb);
            Bs[kkb+0][jj] = vv.x; Bs[kkb+1][jj] = vv.y;
            Bs[kkb+2][jj] = vv.z; Bs[kkb+3][jj] = vv.w;
        }
        __syncthreads();
        #pragma unroll
        for (int kk = 0; kk < 32; ++kk) {
            float a0 = As[kk][tr*4+0], a1 = As[kk][tr*4+1];
            float a2 = As[kk][tr*4+2], a3 = As[kk][tr*4+3];
            float bb0 = Bs[kk][tc*2+0], bb1 = Bs[kk][tc*2+1];
            acc[0][0] += a0*bb0; acc[0][1] += a0*bb1;
            acc[1][0] += a1*bb0; acc[1][1] += a1*bb1;
            acc[2][0] += a2*bb0; acc[2][1] += a2*bb1;
            acc[3][0] += a3*bb0; acc[3][1] += a3*bb1;
        }
        __syncthreads();
    }
    float2 bia = *(const float2*)(bias + j0 + tc*2);
    #pragma unroll
    for (int r = 0; r < 4; ++r) {
        int bb = b0 + tr*4 + r;
        float2 o = make_float2(acc[r][0] + bia.x, acc[r][1] + bia.y);
        *(float2*)(Cmat + (size_t)bb*1024 + j0 + tc*2) = o;
    }
}

// ---------------------------------------------------------------------------
// SGEMM 2: C(512x256) = A(512x1024) x Wo(256x1024)^T + bo
// Tile BM=32, BN=32, BK=32. grid (16, 8).
// ---------------------------------------------------------------------------
__global__ __launch_bounds__(256) void gemm2_kernel(
        const float* __restrict__ Amat, // (512, 1024) row-major
        const float* __restrict__ W,    // (256, 1024)
        const float* __restrict__ bias,
        float* __restrict__ Cmat) {     // (512, 256)
    __shared__ float As[32][33];
    __shared__ float Bs[32][33];
    int b0 = blockIdx.x * 32, j0 = blockIdx.y * 32;
    int tid = threadIdx.x;
    int tr = tid >> 4, tc = tid & 15;
    float acc[2][2] = {};
    for (int k0 = 0; k0 < 1024; k0 += 32) {
        {
            int rr = tid >> 3, kkb = (tid & 7) * 4;
            float4 av = *(const float4*)(Amat + (size_t)(b0 + rr)*1024 + k0 + kkb);
            As[kkb+0][rr] = av.x; As[kkb+1][rr] = av.y;
            As[kkb+2][rr] = av.z; As[kkb+3][rr] = av.w;
            float4 wv = *(const float4*)(W + (size_t)(j0 + rr)*1024 + k0 + kkb);
            Bs[kkb+0][rr] = wv.x; Bs[kkb+1][rr] = wv.y;
            Bs[kkb+2][rr] = wv.z; Bs[kkb+3][rr] = wv.w;
        }
        __syncthreads();
        #pragma unroll
        for (int kk = 0; kk < 32; ++kk) {
            float a0 = As[kk][tr*2+0], a1 = As[kk][tr*2+1];
            float bb0 = Bs[kk][tc*2+0], bb1 = Bs[kk][tc*2+1];
            acc[0][0] += a0*bb0; acc[0][1] += a0*bb1;
            acc[1][0] += a1*bb0; acc[1][1] += a1*bb1;
        }
        __syncthreads();
    }
    float2 bia = *(const float2*)(bias + j0 + tc*2);
    #pragma unroll
    for (int r = 0; r < 2; ++r) {
        int bb = b0 + tr*2 + r;
        float2 o = make_float2(acc[r][0] + bia.x, acc[r][1] + bia.y);
        *(float2*)(Cmat + (size_t)bb*256 + j0 + tc*2) = o;
    }
}

// ---------------------------------------------------------------------------
// LayerNorm (+ReLU) over rows of 1024
// ---------------------------------------------------------------------------
__global__ __launch_bounds__(256) void ln_relu_kernel(
        const float* __restrict__ X, const float* __restrict__ g,
        const float* __restrict__ be, float* __restrict__ Y) {
    int b = blockIdx.x, tid = threadIdx.x;
    __shared__ float2 red[4];
    const float* xr = X + (size_t)b * 1024;
    float v0 = xr[tid], v1 = xr[tid+256], v2 = xr[tid+512], v3 = xr[tid+768];
    float2 v = make_float2(v0+v1+v2+v3, v0*v0+v1*v1+v2*v2+v3*v3);
    int lane = tid & 63, wave = tid >> 6;
    for (int off = 32; off; off >>= 1) { v.x += __shfl_down(v.x, off); v.y += __shfl_down(v.y, off); }
    if (lane == 0) red[wave] = v;
    __syncthreads();
    float s = 0.f, s2 = 0.f;
    #pragma unroll
    for (int wv = 0; wv < 4; ++wv) { s += red[wv].x; s2 += red[wv].y; }
    float mu  = s  * (1.f/1024.f);
    float var = s2 * (1.f/1024.f) - mu*mu;
    float inv = rsqrtf(var + EPS);
    float* yr = Y + (size_t)b * 1024;
    yr[tid]     = fmaxf((v0-mu)*inv*g[tid]     + be[tid],     0.f);
    yr[tid+256] = fmaxf((v1-mu)*inv*g[tid+256] + be[tid+256], 0.f);
    yr[tid+512] = fmaxf((v2-mu)*inv*g[tid+512] + be[tid+512], 0.f);
    yr[tid+768] = fmaxf((v3-mu)*inv*g[tid+768] + be[tid+768], 0.f);
}

// LayerNorm over rows of 256 (final output)
__global__ __launch_bounds__(256) void ln_out_kernel(
        const float* __restrict__ X, const float* __restrict__ g,
        const float* __restrict__ be, float* __restrict__ Y) {
    int b = blockIdx.x, tid = threadIdx.x;
    __shared__ float2 red[4];
    float v0 = X[(size_t)b*256 + tid];
    float2 v = make_float2(v0, v0*v0);
    int lane = tid & 63, wave = tid >> 6;
    for (int off = 32; off; off >>= 1) { v.x += __shfl_down(v.x, off); v.y += __shfl_down(v.y, off); }
    if (lane == 0) red[wave] = v;
    __syncthreads();
    float s = 0.f, s2 = 0.f;
    #pragma unroll
    for (int wv = 0; wv < 4; ++wv) { s += red[wv].x; s2 += red[wv].y; }
    float mu  = s  * (1.f/256.f);
    float var = s2 * (1.f/256.f) - mu*mu;
    Y[(size_t)b*256 + tid] = (v0 - mu) * rsqrtf(var + EPS) * g[tid] + be[tid];
}

// ---------------------------------------------------------------------------
extern "C" void kernel_launch(void* const* d_in, const int* in_sizes, int n_in,
                              void* d_out, int out_size, void* d_ws, size_t ws_size,
                              hipStream_t stream) {
    const float* x    = (const float*)d_in[0];
    const float* qWe0 = (const float*)d_in[1];
    const float* qbe0 = (const float*)d_in[2];
    const float* qgi0 = (const float*)d_in[3];
    const float* qbi0 = (const float*)d_in[4];
    const float* rot0 = (const float*)d_in[5];
    const float* ent0 = (const float*)d_in[6];
    const float* qWd0 = (const float*)d_in[7];
    const float* qbd0 = (const float*)d_in[8];
    const float* qgo0 = (const float*)d_in[9];
    const float* qbo0 = (const float*)d_in[10];
    const float* qWe1 = (const float*)d_in[11];
    const float* qbe1 = (const float*)d_in[12];
    const float* qgi1 = (const float*)d_in[13];
    const float* qbi1 = (const float*)d_in[14];
    const float* rot1 = (const float*)d_in[15];
    const float* ent1 = (const float*)d_in[16];
    const float* qWd1 = (const float*)d_in[17];
    const float* qbd1 = (const float*)d_in[18];
    const float* qgo1 = (const float*)d_in[19];
    const float* qbo1 = (const float*)d_in[20];
    const float* W2   = (const float*)d_in[21];
    const float* b2   = (const float*)d_in[22];
    const float* ln2g = (const float*)d_in[23];
    const float* ln2b = (const float*)d_in[24];
    const float* Wo   = (const float*)d_in[25];
    const float* bo   = (const float*)d_in[26];
    const float* lnog = (const float*)d_in[27];
    const float* lnob = (const float*)d_in[28];
    float* out = (float*)d_out;
    float* ws  = (float*)d_ws;

    // workspace layout (floats)
    float2* Uc = (float2*)ws;            // 288 float2
    float2* Cc = Uc + 288;               // 66 float2  (ends at float 708)
    float* A0  = ws + 1024;              // 512*12
    float* m0  = A0 + 6144;
    float* A1  = m0 + 6144;
    float* m1  = A1 + 6144;              // ends at 25600
    float* Yraw = ws + 25600;            // 512*12 (reused by both layers)
    float* h1T = ws + 32768;             // 512*512 (H1 x B, transposed)
    float* h2T = h1T + 262144;           // 512*512
    float* t3  = h2T + 262144;           // 512*1024
    float* t3n = t3 + 524288;            // 512*1024
    float* t4  = t3n + 524288;           // 512*256
    // total ~6.95 MB

    hipLaunchKernelGGL(consts_kernel, dim3(1), dim3(256), 0, stream,
                       rot0, ent0, rot1, ent1, Uc, Cc);

    // layer 0
    hipLaunchKernelGGL(encode_rm_kernel, dim3(128), dim3(256), 0, stream,
                       x, qWe0, qbe0, Yraw);
    hipLaunchKernelGGL(bn_tanh_kernel, dim3(1), dim3(512), 0, stream,
                       Yraw, qgi0, qbi0, A0);
    hipLaunchKernelGGL(qsim_kernel, dim3(512), dim3(256), 0, stream,
                       A0, Uc, Cc, 0, m0);
    hipLaunchKernelGGL(decode_kernel, dim3(512), dim3(512), 0, stream,
                       m0, qWd0, qbd0, qgo0, qbo0, h1T);

    // layer 1 (reads k-major h1T with coalesced rows)
    hipLaunchKernelGGL(encode_cm_kernel, dim3(8), dim3(256), 0, stream,
                       h1T, qWe1, qbe1, Yraw);
    hipLaunchKernelGGL(bn_tanh_kernel, dim3(1), dim3(512), 0, stream,
                       Yraw, qgi1, qbi1, A1);
    hipLaunchKernelGGL(qsim_kernel, dim3(512), dim3(256), 0, stream,
                       A1, Uc, Cc, 1, m1);
    hipLaunchKernelGGL(decode_kernel, dim3(512), dim3(512), 0, stream,
                       m1, qWd1, qbd1, qgo1, qbo1, h2T);

    // MLP head
    hipLaunchKernelGGL(gemm1_kernel, dim3(8, 32), dim3(256), 0, stream,
                       h2T, W2, b2, t3);
    hipLaunchKernelGGL(ln_relu_kernel, dim3(512), dim3(256), 0, stream,
                       t3, ln2g, ln2b, t3n);
    hipLaunchKernelGGL(gemm2_kernel, dim3(16, 8), dim3(256), 0, stream,
                       t3n, Wo, bo, t4);
    hipLaunchKernelGGL(ln_out_kernel, dim3(512), dim3(256), 0, stream,
                       t4, lnog, lnob, out);
}

// Round 4
// 235.147 us; speedup vs baseline: 1.8434x; 1.3888x over previous
//
#include <hip/hip_runtime.h>
#include <math.h>

#define EPS   1e-5f
#define NQ    12
#define DEPTH 3
#define BATCH 512
#define DIM   4096   // 2^NQ

__device__ inline float2 cmul(float2 a, float2 b) {
    return make_float2(a.x*b.x - a.y*b.y, a.x*b.y + a.y*b.x);
}
__device__ inline float2 cmac2(float2 ua, float2 s, float2 ub, float2 p) {
    return make_float2(ua.x*s.x - ua.y*s.y + ub.x*p.x - ub.y*p.y,
                       ua.x*s.y + ua.y*s.x + ub.x*p.y + ub.y*p.x);
}

// ---------------------------------------------------------------------------
// Precompute U = Rz@Ry@Rx (2 layers x 3 depth x 12 qubits) and CRY cos/sin.
// ---------------------------------------------------------------------------
__global__ void consts_kernel(const float* __restrict__ rot0, const float* __restrict__ ent0,
                              const float* __restrict__ rot1, const float* __restrict__ ent1,
                              float2* __restrict__ Uc, float2* __restrict__ Cc) {
    int t = threadIdx.x;
    if (t < 72) {
        int layer = t / 36, rem = t % 36, d = rem / 12, q = rem % 12;
        const float* rot = layer ? rot1 : rot0;
        float hx = 0.5f * rot[(d*NQ + q)*3 + 0];
        float hy = 0.5f * rot[(d*NQ + q)*3 + 1];
        float hz = 0.5f * rot[(d*NQ + q)*3 + 2];
        float cx = cosf(hx), sx = sinf(hx);
        float cy = cosf(hy), sy = sinf(hy);
        float2 m00 = make_float2( cy*cx,  sy*sx);
        float2 m01 = make_float2(-sy*cx, -cy*sx);
        float2 m10 = make_float2( sy*cx, -cy*sx);
        float2 m11 = make_float2( cy*cx, -sy*sx);
        float2 ez  = make_float2(cosf(hz), -sinf(hz));
        float2 ezc = make_float2(ez.x, -ez.y);
        float2* U = Uc + t*4;
        U[0] = cmul(ez,  m00);
        U[1] = cmul(ez,  m01);
        U[2] = cmul(ezc, m10);
        U[3] = cmul(ezc, m11);
    } else if (t < 72 + 66) {
        int idx = t - 72, layer = idx / 33, rem = idx % 33;
        const float* ent = layer ? ent1 : ent0;
        float th = 0.5f * ent[rem];
        Cc[idx] = make_float2(cosf(th), sinf(th));
    }
}

// ---------------------------------------------------------------------------
// Encode GEMM, row-major X (B x 512). One wave per batch row. grid = 128.
// ---------------------------------------------------------------------------
__global__ __launch_bounds__(256) void encode_rm_kernel(
        const float* __restrict__ X, const float* __restrict__ We,
        const float* __restrict__ be, float* __restrict__ Yraw) {
    __shared__ float w[NQ][512];
    int tid = threadIdx.x;
    {
        const float4* src = (const float4*)We;
        float4* dst = (float4*)&w[0][0];
        #pragma unroll
        for (int i = tid; i < NQ*512/4; i += 256) dst[i] = src[i];
    }
    __syncthreads();
    int wave = tid >> 6, lane = tid & 63;
    int b = blockIdx.x * 4 + wave;
    const float4* xr = (const float4*)(X + (size_t)b * 512);
    float acc[NQ] = {};
    #pragma unroll
    for (int j = 0; j < 2; ++j) {
        float4 xv = xr[lane + 64*j];
        #pragma unroll
        for (int q = 0; q < NQ; ++q) {
            float4 wv = ((const float4*)&w[q][0])[lane + 64*j];
            acc[q] += xv.x*wv.x + xv.y*wv.y + xv.z*wv.z + xv.w*wv.w;
        }
    }
    #pragma unroll
    for (int q = 0; q < NQ; ++q) {
        float v = acc[q];
        #pragma unroll
        for (int off = 32; off; off >>= 1) v += __shfl_xor(v, off);
        if (lane == q) Yraw[b*NQ + q] = v + be[q];
    }
}

// ---------------------------------------------------------------------------
// Batch-BN (512 rows x 12 cols) + tanh. One 512-thread block.
// ---------------------------------------------------------------------------
__global__ __launch_bounds__(512) void bn_tanh_kernel(
        const float* __restrict__ Yraw,
        const float* __restrict__ gi, const float* __restrict__ bi,
        float* __restrict__ A) {
    int b = threadIdx.x;
    float v[NQ];
    #pragma unroll
    for (int q = 0; q < NQ; ++q) v[q] = Yraw[b*NQ + q];
    __shared__ float2 red[NQ][8];
    int lane = b & 63, wave = b >> 6;
    #pragma unroll
    for (int q = 0; q < NQ; ++q) {
        float2 t = make_float2(v[q], v[q]*v[q]);
        for (int off = 32; off; off >>= 1) { t.x += __shfl_down(t.x, off); t.y += __shfl_down(t.y, off); }
        if (lane == 0) red[q][wave] = t;
    }
    __syncthreads();
    #pragma unroll
    for (int q = 0; q < NQ; ++q) {
        float s = 0.f, s2 = 0.f;
        #pragma unroll
        for (int wv = 0; wv < 8; ++wv) { s += red[q][wv].x; s2 += red[q][wv].y; }
        float mu  = s  * (1.f/512.f);
        float var = s2 * (1.f/512.f) - mu*mu;
        A[b*NQ + q] = tanhf((v[q] - mu) * rsqrtf(var + EPS) * gi[q] + bi[q]);
    }
}

// ---------------------------------------------------------------------------
// Quantum sim, window-remap version. 256 thr/sample, 16 float2 amps/thread.
// Layouts (which amp bits live in the k-register index):
//   L1: amp = (k<<8)|tid         k bits = amp[11:8] = qubits 0..3
//   L2: amp = tid[7:5]<<9 | k<<5 | tid[4:0]   k = amp[8:5] = qubits 3..6
//   L3: amp = tid[7:2]<<6 | k<<2 | tid[1:0]   k = amp[5:2] = qubits 6..9
//   L4: amp = (tid<<4)|k         k bits = amp[3:0] = qubits 8..11
// All gates are register butterflies; remaps are full-state LDS permutes.
// Gates on disjoint qubits commute => interleaving 1q into windows is exact.
// ---------------------------------------------------------------------------
__device__ inline int swz(int a) { return a ^ ((a >> 4) & 15); }

template<int L> __device__ inline int ampl(int tid, int k) {
    if constexpr (L == 1) return (k << 8) | tid;
    else if constexpr (L == 2) return ((tid & 0xE0) << 4) | (k << 5) | (tid & 0x1F);
    else if constexpr (L == 3) return ((tid & 0xFC) << 4) | (k << 2) | (tid & 3);
    else return (tid << 4) | k;
}

template<int F, int T>
__device__ inline void remap(float2* amp, float2* lds2, int tid) {
    #pragma unroll
    for (int k = 0; k < 16; ++k) lds2[swz(ampl<F>(tid, k))] = amp[k];
    __syncthreads();
    #pragma unroll
    for (int k = 0; k < 16; ++k) amp[k] = lds2[swz(ampl<T>(tid, k))];
    __syncthreads();
}

template<int BP>
__device__ inline void one_q(float2* amp, float2 u00, float2 u01, float2 u10, float2 u11) {
    #pragma unroll
    for (int g = 0; g < 8; ++g) {
        const int j0 = ((g >> BP) << (BP+1)) | (g & ((1<<BP)-1));
        const int j1 = j0 | (1 << BP);
        float2 a0 = amp[j0], a1 = amp[j1];
        amp[j0] = cmac2(u00, a0, u01, a1);
        amp[j1] = cmac2(u10, a0, u11, a1);
    }
}

template<int CB, int TB>
__device__ inline void cry_rr(float2* amp, float co, float si) {
    #pragma unroll
    for (int m = 0; m < 16; ++m) {
        if (((m >> CB) & 1) && !((m >> TB) & 1)) {
            const int j1 = m | (1 << TB);
            float2 a0 = amp[m], a1 = amp[j1];
            amp[m]  = make_float2(co*a0.x - si*a1.x, co*a0.y - si*a1.y);
            amp[j1] = make_float2(si*a0.x + co*a1.x, si*a0.y + co*a1.y);
        }
    }
}

__global__ __launch_bounds__(256) void qsim_kernel(
        const float* __restrict__ A, const float2* __restrict__ UcAll,
        const float2* __restrict__ CcAll, int layer, float* __restrict__ mout) {
    int b = blockIdx.x, tid = threadIdx.x;
    const float2* Uc = UcAll + layer * DEPTH * NQ * 4;
    const float2* Cc = CcAll + layer * DEPTH * (NQ - 1);
    __shared__ float2 lds2[DIM];
    __shared__ float red[NQ][4];

    // per-qubit init vectors (encode RY fused with depth-0 rotation U)
    float av[NQ]; float n2 = 0.f;
    #pragma unroll
    for (int q = 0; q < NQ; ++q) { av[q] = A[b*NQ + q]; n2 += av[q]*av[q]; }
    float scn = (n2 > 0.f) ? rsqrtf(n2) : 1.f;
    float2 v0[NQ], v1[NQ];
    #pragma unroll
    for (int q = 0; q < NQ; ++q) {
        float a  = av[q] * scn;
        float sv = fminf(fabsf(a), 1.f);
        float c  = sqrtf(fmaxf(1.f - sv*sv, 0.f));
        float ss = (a < 0.f) ? -sv : sv;
        const float2* U = Uc + q*4;   // d = 0 fused
        v0[q] = make_float2(U[0].x*c + U[1].x*ss, U[0].y*c + U[1].y*ss);
        v1[q] = make_float2(U[2].x*c + U[3].x*ss, U[2].y*c + U[3].y*ss);
    }
    // Product state in L1: tid bit bb = amp bit bb = qubit 11-bb
    float2 common = make_float2(1.f, 0.f);
    #pragma unroll
    for (int bb = 0; bb < 8; ++bb)
        common = cmul(common, ((tid >> bb) & 1) ? v1[11-bb] : v0[11-bb]);
    // k bit m = amp bit 8+m = qubit 3-m
    float2 amp[16];
    amp[0] = common;
    #pragma unroll
    for (int m = 0; m < 4; ++m) {
        const int q = 3 - m;
        #pragma unroll
        for (int k = 0; k < (1<<m); ++k) {
            amp[k | (1<<m)] = cmul(amp[k], v1[q]);
            amp[k]          = cmul(amp[k], v0[q]);
        }
    }

    for (int d = 0; d < DEPTH; ++d) {
        const float2* Ud = Uc + d*NQ*4;
        const float2* Cd = Cc + d*(NQ-1);
        // ---- window W1: regs = qubits 0..3 (k bit m = qubit 3-m) ----
        if (d > 0) {
            remap<4,1>(amp, lds2, tid);
            one_q<3>(amp, Ud[0],  Ud[1],  Ud[2],  Ud[3]);   // U0
            one_q<2>(amp, Ud[4],  Ud[5],  Ud[6],  Ud[7]);   // U1
            one_q<1>(amp, Ud[8],  Ud[9],  Ud[10], Ud[11]);  // U2
            one_q<0>(amp, Ud[12], Ud[13], Ud[14], Ud[15]);  // U3
        }
        cry_rr<3,2>(amp, Cd[0].x, Cd[0].y);   // CRY 0-1
        cry_rr<2,1>(amp, Cd[1].x, Cd[1].y);   // CRY 1-2
        cry_rr<1,0>(amp, Cd[2].x, Cd[2].y);   // CRY 2-3
        // ---- window W2: regs = qubits 3..6 (k bit m = qubit 6-m) ----
        remap<1,2>(amp, lds2, tid);
        if (d > 0) {
            one_q<2>(amp, Ud[16], Ud[17], Ud[18], Ud[19]);  // U4
            one_q<1>(amp, Ud[20], Ud[21], Ud[22], Ud[23]);  // U5
            one_q<0>(amp, Ud[24], Ud[25], Ud[26], Ud[27]);  // U6
        }
        cry_rr<3,2>(amp, Cd[3].x, Cd[3].y);   // CRY 3-4
        cry_rr<2,1>(amp, Cd[4].x, Cd[4].y);   // CRY 4-5
        cry_rr<1,0>(amp, Cd[5].x, Cd[5].y);   // CRY 5-6
        // ---- window W3: regs = qubits 6..9 (k bit m = qubit 9-m) ----
        remap<2,3>(amp, lds2, tid);
        if (d > 0) {
            one_q<2>(amp, Ud[28], Ud[29], Ud[30], Ud[31]);  // U7
            one_q<1>(amp, Ud[32], Ud[33], Ud[34], Ud[35]);  // U8
            one_q<0>(amp, Ud[36], Ud[37], Ud[38], Ud[39]);  // U9
        }
        cry_rr<3,2>(amp, Cd[6].x, Cd[6].y);   // CRY 6-7
        cry_rr<2,1>(amp, Cd[7].x, Cd[7].y);   // CRY 7-8
        cry_rr<1,0>(amp, Cd[8].x, Cd[8].y);   // CRY 8-9
        // ---- window W4: regs = qubits 8..11 (k bit m = qubit 11-m) ----
        remap<3,4>(amp, lds2, tid);
        if (d > 0) {
            one_q<1>(amp, Ud[40], Ud[41], Ud[42], Ud[43]);  // U10
            one_q<0>(amp, Ud[44], Ud[45], Ud[46], Ud[47]);  // U11
        }
        cry_rr<2,1>(amp, Cd[9].x,  Cd[9].y);  // CRY 9-10
        cry_rr<1,0>(amp, Cd[10].x, Cd[10].y); // CRY 10-11
    }

    // measurement in L4 (= original layout)
    float msum = 0.f, p8 = 0.f, p9 = 0.f, p10 = 0.f, p11 = 0.f;
    #pragma unroll
    for (int k = 0; k < 16; ++k) {
        float m = amp[k].x*amp[k].x + amp[k].y*amp[k].y;
        msum += m;
        if (k & 8) p8  += m;
        if (k & 4) p9  += m;
        if (k & 2) p10 += m;
        if (k & 1) p11 += m;
    }
    int lane = tid & 63, wave = tid >> 6;
    #pragma unroll
    for (int q = 0; q < NQ; ++q) {
        float v;
        if (q < 8)        v = ((tid >> (7-q)) & 1) ? msum : 0.f;
        else if (q == 8)  v = p8;
        else if (q == 9)  v = p9;
        else if (q == 10) v = p10;
        else              v = p11;
        #pragma unroll
        for (int off = 32; off; off >>= 1) v += __shfl_xor(v, off);
        if (lane == 0) red[q][wave] = v;
    }
    __syncthreads();
    if (tid < NQ)
        mout[b*NQ + tid] = red[tid][0] + red[tid][1] + red[tid][2] + red[tid][3];
}

// ---------------------------------------------------------------------------
// Decode: Z[:,h] = m @ Wd[h] + bd[h]; BN over batch; write transposed (H x B).
// ---------------------------------------------------------------------------
__global__ __launch_bounds__(512) void decode_kernel(
        const float* __restrict__ m, const float* __restrict__ Wd,
        const float* __restrict__ bd, const float* __restrict__ go,
        const float* __restrict__ bo, float* __restrict__ outT) {
    int h = blockIdx.x, b = threadIdx.x;
    __shared__ float sm[BATCH * 13];     // stride 13: conflict-free
    __shared__ float2 red[8];
    for (int idx = b; idx < BATCH * NQ; idx += 512) {
        int bb = idx / NQ, q = idx - bb * NQ;
        sm[bb*13 + q] = m[idx];
    }
    __syncthreads();
    float z = bd[h];
    #pragma unroll
    for (int q = 0; q < NQ; ++q) z += sm[b*13 + q] * Wd[h*NQ + q];

    float2 v = make_float2(z, z*z);
    int lane = b & 63, wave = b >> 6;
    for (int off = 32; off; off >>= 1) { v.x += __shfl_down(v.x, off); v.y += __shfl_down(v.y, off); }
    if (lane == 0) red[wave] = v;
    __syncthreads();
    float s = 0.f, s2 = 0.f;
    #pragma unroll
    for (int wv = 0; wv < 8; ++wv) { s += red[wv].x; s2 += red[wv].y; }
    float mu  = s  * (1.f/512.f);
    float var = s2 * (1.f/512.f) - mu*mu;
    outT[(size_t)h*BATCH + b] = (z - mu) * rsqrtf(var + EPS) * go[h] + bo[h];
}

// ---------------------------------------------------------------------------
// Transpose 512x512: out[b][h] = in[h][b]. 64 blocks, 64x64 tiles.
// ---------------------------------------------------------------------------
__global__ __launch_bounds__(256) void transpose512_kernel(
        const float* __restrict__ in, float* __restrict__ out) {
    __shared__ float t[64][68];
    int tx = blockIdx.x & 7, ty = blockIdx.x >> 3;   // b-tile, h-tile
    int tid = threadIdx.x;
    int c4 = (tid & 15) * 4, rr = tid >> 4;
    #pragma unroll
    for (int i = 0; i < 4; ++i) {
        int h = ty*64 + rr + i*16;
        float4 v = *(const float4*)(in + (size_t)h*512 + tx*64 + c4);
        t[c4+0][rr+i*16] = v.x; t[c4+1][rr+i*16] = v.y;
        t[c4+2][rr+i*16] = v.z; t[c4+3][rr+i*16] = v.w;
    }
    __syncthreads();
    #pragma unroll
    for (int i = 0; i < 4; ++i) {
        int bb = tx*64 + rr + i*16;
        float4 o = *(const float4*)&t[rr+i*16][c4];
        *(float4*)(out + (size_t)bb*512 + ty*64 + c4) = o;
    }
}

// ---------------------------------------------------------------------------
// GEMM1 split-K: Cpart[z] = AT-slice^T x W2-slice^T. BM=64,BN=64,BK=32,
// acc 4x4, double-buffered LDS. grid (8,16,2), 256 thr.
// ---------------------------------------------------------------------------
__global__ __launch_bounds__(256) void gemm1_kernel(
        const float* __restrict__ AT,   // (512 K-rows, 512 B-cols)
        const float* __restrict__ W,    // (1024, 512)
        float* __restrict__ Cpart) {    // [2][512][1024]
    __shared__ float As[2][32][64];
    __shared__ float Bs[2][32][68];
    const int b0 = blockIdx.x * 64, j0 = blockIdx.y * 64;
    const int kbase = blockIdx.z * 256;
    float* C = Cpart + (size_t)blockIdx.z * 512 * 1024;
    const int tid = threadIdx.x;
    const int tr = tid >> 4, tc = tid & 15;
    const int a_kk = tid >> 4, a_f4 = tid & 15;
    const int b_jj = tid >> 3, b_k4 = (tid & 7) * 4;
    float4 ra0, ra1, rb0, rb1;
    float acc[4][4] = {};

    {   // prologue: stage step 0
        const int k0 = kbase;
        ra0 = *(const float4*)(AT + (size_t)(k0 + a_kk)*512 + b0 + a_f4*4);
        ra1 = *(const float4*)(AT + (size_t)(k0 + a_kk + 16)*512 + b0 + a_f4*4);
        rb0 = *(const float4*)(W + (size_t)(j0 + b_jj)*512 + k0 + b_k4);
        rb1 = *(const float4*)(W + (size_t)(j0 + b_jj + 32)*512 + k0 + b_k4);
        *(float4*)&As[0][a_kk][a_f4*4] = ra0;
        *(float4*)&As[0][a_kk+16][a_f4*4] = ra1;
        Bs[0][b_k4+0][b_jj] = rb0.x; Bs[0][b_k4+1][b_jj] = rb0.y;
        Bs[0][b_k4+2][b_jj] = rb0.z; Bs[0][b_k4+3][b_jj] = rb0.w;
        Bs[0][b_k4+0][b_jj+32] = rb1.x; Bs[0][b_k4+1][b_jj+32] = rb1.y;
        Bs[0][b_k4+2][b_jj+32] = rb1.z; Bs[0][b_k4+3][b_jj+32] = rb1.w;
    }
    __syncthreads();
    for (int s = 0; s < 8; ++s) {
        if (s < 7) {
            const int k0 = kbase + (s+1)*32;
            ra0 = *(const float4*)(AT + (size_t)(k0 + a_kk)*512 + b0 + a_f4*4);
            ra1 = *(const float4*)(AT + (size_t)(k0 + a_kk + 16)*512 + b0 + a_f4*4);
            rb0 = *(const float4*)(W + (size_t)(j0 + b_jj)*512 + k0 + b_k4);
            rb1 = *(const float4*)(W + (size_t)(j0 + b_jj + 32)*512 + k0 + b_k4);
        }
        const int bf = s & 1;
        #pragma unroll
        for (int kk = 0; kk < 32; ++kk) {
            float4 a  = *(const float4*)&As[bf][kk][tr*4];
            float4 bv = *(const float4*)&Bs[bf][kk][tc*4];
            acc[0][0] += a.x*bv.x; acc[0][1] += a.x*bv.y; acc[0][2] += a.x*bv.z; acc[0][3] += a.x*bv.w;
            acc[1][0] += a.y*bv.x; acc[1][1] += a.y*bv.y; acc[1][2] += a.y*bv.z; acc[1][3] += a.y*bv.w;
            acc[2][0] += a.z*bv.x; acc[2][1] += a.z*bv.y; acc[2][2] += a.z*bv.z; acc[2][3] += a.z*bv.w;
            acc[3][0] += a.w*bv.x; acc[3][1] += a.w*bv.y; acc[3][2] += a.w*bv.z; acc[3][3] += a.w*bv.w;
        }
        if (s < 7) {
            const int nb = bf ^ 1;
            *(float4*)&As[nb][a_kk][a_f4*4] = ra0;
            *(float4*)&As[nb][a_kk+16][a_f4*4] = ra1;
            Bs[nb][b_k4+0][b_jj] = rb0.x; Bs[nb][b_k4+1][b_jj] = rb0.y;
            Bs[nb][b_k4+2][b_jj] = rb0.z; Bs[nb][b_k4+3][b_jj] = rb0.w;
            Bs[nb][b_k4+0][b_jj+32] = rb1.x; Bs[nb][b_k4+1][b_jj+32] = rb1.y;
            Bs[nb][b_k4+2][b_jj+32] = rb1.z; Bs[nb][b_k4+3][b_jj+32] = rb1.w;
        }
        __syncthreads();
    }
    #pragma unroll
    for (int r = 0; r < 4; ++r) {
        float4 o = make_float4(acc[r][0], acc[r][1], acc[r][2], acc[r][3]);
        *(float4*)(C + (size_t)(b0 + tr*4 + r)*1024 + j0 + tc*4) = o;
    }
}

// ---------------------------------------------------------------------------
// GEMM2 split-K8: Cpart[z] = A-slice x Wo-slice^T. A row-major (512,1024).
// BM=64,BN=64,BK=32, 4 k-steps. grid (8,4,8), 256 thr.
// ---------------------------------------------------------------------------
__global__ __launch_bounds__(256) void gemm2_kernel(
        const float* __restrict__ Amat, // (512, 1024) row-major
        const float* __restrict__ W,    // (256, 1024)
        float* __restrict__ Cpart) {    // [8][512][256]
    __shared__ float As[2][32][68];
    __shared__ float Bs[2][32][68];
    const int b0 = blockIdx.x * 64, j0 = blockIdx.y * 64;
    const int kbase = blockIdx.z * 128;
    float* C = Cpart + (size_t)blockIdx.z * 512 * 256;
    const int tid = threadIdx.x;
    const int tr = tid >> 4, tc = tid & 15;
    const int l_r = tid >> 3, l_k4 = (tid & 7) * 4;
    float4 ra0, ra1, rb0, rb1;
    float acc[4][4] = {};

    {
        const int k0 = kbase;
        ra0 = *(const float4*)(Amat + (size_t)(b0 + l_r)*1024 + k0 + l_k4);
        ra1 = *(const float4*)(Amat + (size_t)(b0 + l_r + 32)*1024 + k0 + l_k4);
        rb0 = *(const float4*)(W + (size_t)(j0 + l_r)*1024 + k0 + l_k4);
        rb1 = *(const float4*)(W + (size_t)(j0 + l_r + 32)*1024 + k0 + l_k4);
        As[0][l_k4+0][l_r] = ra0.x; As[0][l_k4+1][l_r] = ra0.y;
        As[0][l_k4+2][l_r] = ra0.z; As[0][l_k4+3][l_r] = ra0.w;
        As[0][l_k4+0][l_r+32] = ra1.x; As[0][l_k4+1][l_r+32] = ra1.y;
        As[0][l_k4+2][l_r+32] = ra1.z; As[0][l_k4+3][l_r+32] = ra1.w;
        Bs[0][l_k4+0][l_r] = rb0.x; Bs[0][l_k4+1][l_r] = rb0.y;
        Bs[0][l_k4+2][l_r] = rb0.z; Bs[0][l_k4+3][l_r] = rb0.w;
        Bs[0][l_k4+0][l_r+32] = rb1.x; Bs[0][l_k4+1][l_r+32] = rb1.y;
        Bs[0][l_k4+2][l_r+32] = rb1.z; Bs[0][l_k4+3][l_r+32] = rb1.w;
    }
    __syncthreads();
    for (int s = 0; s < 4; ++s) {
        if (s < 3) {
            const int k0 = kbase + (s+1)*32;
            ra0 = *(const float4*)(Amat + (size_t)(b0 + l_r)*1024 + k0 + l_k4);
            ra1 = *(const float4*)(Amat + (size_t)(b0 + l_r + 32)*1024 + k0 + l_k4);
            rb0 = *(const float4*)(W + (size_t)(j0 + l_r)*1024 + k0 + l_k4);
            rb1 = *(const float4*)(W + (size_t)(j0 + l_r + 32)*1024 + k0 + l_k4);
        }
        const int bf = s & 1;
        #pragma unroll
        for (int kk = 0; kk < 32; ++kk) {
            float4 a  = *(const float4*)&As[bf][kk][tr*4];
            float4 bv = *(const float4*)&Bs[bf][kk][tc*4];
            acc[0][0] += a.x*bv.x; acc[0][1] += a.x*bv.y; acc[0][2] += a.x*bv.z; acc[0][3] += a.x*bv.w;
            acc[1][0] += a.y*bv.x; acc[1][1] += a.y*bv.y; acc[1][2] += a.y*bv.z; acc[1][3] += a.y*bv.w;
            acc[2][0] += a.z*bv.x; acc[2][1] += a.z*bv.y; acc[2][2] += a.z*bv.z; acc[2][3] += a.z*bv.w;
            acc[3][0] += a.w*bv.x; acc[3][1] += a.w*bv.y; acc[3][2] += a.w*bv.z; acc[3][3] += a.w*bv.w;
        }
        if (s < 3) {
            const int nb = bf ^ 1;
            As[nb][l_k4+0][l_r] = ra0.x; As[nb][l_k4+1][l_r] = ra0.y;
            As[nb][l_k4+2][l_r] = ra0.z; As[nb][l_k4+3][l_r] = ra0.w;
            As[nb][l_k4+0][l_r+32] = ra1.x; As[nb][l_k4+1][l_r+32] = ra1.y;
            As[nb][l_k4+2][l_r+32] = ra1.z; As[nb][l_k4+3][l_r+32] = ra1.w;
            Bs[nb][l_k4+0][l_r] = rb0.x; Bs[nb][l_k4+1][l_r] = rb0.y;
            Bs[nb][l_k4+2][l_r] = rb0.z; Bs[nb][l_k4+3][l_r] = rb0.w;
            Bs[nb][l_k4+0][l_r+32] = rb1.x; Bs[nb][l_k4+1][l_r+32] = rb1.y;
            Bs[nb][l_k4+2][l_r+32] = rb1.z; Bs[nb][l_k4+3][l_r+32] = rb1.w;
        }
        __syncthreads();
    }
    #pragma unroll
    for (int r = 0; r < 4; ++r) {
        float4 o = make_float4(acc[r][0], acc[r][1], acc[r][2], acc[r][3]);
        *(float4*)(C + (size_t)(b0 + tr*4 + r)*256 + j0 + tc*4) = o;
    }
}

// ---------------------------------------------------------------------------
// LayerNorm+ReLU over rows of 1024; input = sum of 2 K-partials + bias.
// ---------------------------------------------------------------------------
__global__ __launch_bounds__(256) void ln_relu_kernel(
        const float* __restrict__ P,    // [2][512][1024]
        const float* __restrict__ bias,
        const float* __restrict__ g, const float* __restrict__ be,
        float* __restrict__ Y) {
    int b = blockIdx.x, tid = threadIdx.x;
    __shared__ float2 red[4];
    const float* p0 = P + (size_t)b * 1024;
    const float* p1 = P + 524288 + (size_t)b * 1024;
    float v0 = p0[tid]     + p1[tid]     + bias[tid];
    float v1 = p0[tid+256] + p1[tid+256] + bias[tid+256];
    float v2 = p0[tid+512] + p1[tid+512] + bias[tid+512];
    float v3 = p0[tid+768] + p1[tid+768] + bias[tid+768];
    float2 v = make_float2(v0+v1+v2+v3, v0*v0+v1*v1+v2*v2+v3*v3);
    int lane = tid & 63, wave = tid >> 6;
    for (int off = 32; off; off >>= 1) { v.x += __shfl_down(v.x, off); v.y += __shfl_down(v.y, off); }
    if (lane == 0) red[wave] = v;
    __syncthreads();
    float s = 0.f, s2 = 0.f;
    #pragma unroll
    for (int wv = 0; wv < 4; ++wv) { s += red[wv].x; s2 += red[wv].y; }
    float mu  = s  * (1.f/1024.f);
    float var = s2 * (1.f/1024.f) - mu*mu;
    float inv = rsqrtf(var + EPS);
    float* yr = Y + (size_t)b * 1024;
    yr[tid]     = fmaxf((v0-mu)*inv*g[tid]     + be[tid],     0.f);
    yr[tid+256] = fmaxf((v1-mu)*inv*g[tid+256] + be[tid+256], 0.f);
    yr[tid+512] = fmaxf((v2-mu)*inv*g[tid+512] + be[tid+512], 0.f);
    yr[tid+768] = fmaxf((v3-mu)*inv*g[tid+768] + be[tid+768], 0.f);
}

// LayerNorm over rows of 256; input = sum of 8 K-partials + bias.
__global__ __launch_bounds__(256) void ln_out_kernel(
        const float* __restrict__ P,    // [8][512][256]
        const float* __restrict__ bias,
        const float* __restrict__ g, const float* __restrict__ be,
        float* __restrict__ Y) {
    int b = blockIdx.x, tid = threadIdx.x;
    __shared__ float2 red[4];
    float v0 = bias[tid];
    #pragma unroll
    for (int z = 0; z < 8; ++z) v0 += P[(size_t)z*131072 + (size_t)b*256 + tid];
    float2 v = make_float2(v0, v0*v0);
    int lane = tid & 63, wave = tid >> 6;
    for (int off = 32; off; off >>= 1) { v.x += __shfl_down(v.x, off); v.y += __shfl_down(v.y, off); }
    if (lane == 0) red[wave] = v;
    __syncthreads();
    float s = 0.f, s2 = 0.f;
    #pragma unroll
    for (int wv = 0; wv < 4; ++wv) { s += red[wv].x; s2 += red[wv].y; }
    float mu  = s  * (1.f/256.f);
    float var = s2 * (1.f/256.f) - mu*mu;
    Y[(size_t)b*256 + tid] = (v0 - mu) * rsqrtf(var + EPS) * g[tid] + be[tid];
}

// ---------------------------------------------------------------------------
extern "C" void kernel_launch(void* const* d_in, const int* in_sizes, int n_in,
                              void* d_out, int out_size, void* d_ws, size_t ws_size,
                              hipStream_t stream) {
    const float* x    = (const float*)d_in[0];
    const float* qWe0 = (const float*)d_in[1];
    const float* qbe0 = (const float*)d_in[2];
    const float* qgi0 = (const float*)d_in[3];
    const float* qbi0 = (const float*)d_in[4];
    const float* rot0 = (const float*)d_in[5];
    const float* ent0 = (const float*)d_in[6];
    const float* qWd0 = (const float*)d_in[7];
    const float* qbd0 = (const float*)d_in[8];
    const float* qgo0 = (const float*)d_in[9];
    const float* qbo0 = (const float*)d_in[10];
    const float* qWe1 = (const float*)d_in[11];
    const float* qbe1 = (const float*)d_in[12];
    const float* qgi1 = (const float*)d_in[13];
    const float* qbi1 = (const float*)d_in[14];
    const float* rot1 = (const float*)d_in[15];
    const float* ent1 = (const float*)d_in[16];
    const float* qWd1 = (const float*)d_in[17];
    const float* qbd1 = (const float*)d_in[18];
    const float* qgo1 = (const float*)d_in[19];
    const float* qbo1 = (const float*)d_in[20];
    const float* W2   = (const float*)d_in[21];
    const float* b2   = (const float*)d_in[22];
    const float* ln2g = (const float*)d_in[23];
    const float* ln2b = (const float*)d_in[24];
    const float* Wo   = (const float*)d_in[25];
    const float* bo   = (const float*)d_in[26];
    const float* lnog = (const float*)d_in[27];
    const float* lnob = (const float*)d_in[28];
    float* out = (float*)d_out;
    float* ws  = (float*)d_ws;

    // workspace layout (floats)
    float2* Uc = (float2*)ws;            // 288 float2
    float2* Cc = Uc + 288;               // 66 float2
    float* A0   = ws + 1024;
    float* m0   = ws + 7168;
    float* A1   = ws + 13312;
    float* m1   = ws + 19456;
    float* Yraw = ws + 25600;
    float* h1T  = ws + 32768;            // 262144   (overlaid later by h2T)
    float* h1   = ws + 294912;           // 262144
    float* h2T  = ws + 32768;            // overlay: h1T dead after transpose
    float* t3p  = ws + 557056;           // 2 x 524288
    float* t3n  = ws + 1605632;          // 524288
    float* t4p  = ws + 557056;           // overlay t3p: 8 x 131072
    // total 2,129,920 floats ~= 8.5 MB

    hipLaunchKernelGGL(consts_kernel, dim3(1), dim3(256), 0, stream,
                       rot0, ent0, rot1, ent1, Uc, Cc);

    // layer 0
    hipLaunchKernelGGL(encode_rm_kernel, dim3(128), dim3(256), 0, stream,
                       x, qWe0, qbe0, Yraw);
    hipLaunchKernelGGL(bn_tanh_kernel, dim3(1), dim3(512), 0, stream,
                       Yraw, qgi0, qbi0, A0);
    hipLaunchKernelGGL(qsim_kernel, dim3(512), dim3(256), 0, stream,
                       A0, Uc, Cc, 0, m0);
    hipLaunchKernelGGL(decode_kernel, dim3(512), dim3(512), 0, stream,
                       m0, qWd0, qbd0, qgo0, qbo0, h1T);
    hipLaunchKernelGGL(transpose512_kernel, dim3(64), dim3(256), 0, stream,
                       h1T, h1);

    // layer 1
    hipLaunchKernelGGL(encode_rm_kernel, dim3(128), dim3(256), 0, stream,
                       h1, qWe1, qbe1, Yraw);
    hipLaunchKernelGGL(bn_tanh_kernel, dim3(1), dim3(512), 0, stream,
                       Yraw, qgi1, qbi1, A1);
    hipLaunchKernelGGL(qsim_kernel, dim3(512), dim3(256), 0, stream,
                       A1, Uc, Cc, 1, m1);
    hipLaunchKernelGGL(decode_kernel, dim3(512), dim3(512), 0, stream,
                       m1, qWd1, qbd1, qgo1, qbo1, h2T);

    // MLP head
    hipLaunchKernelGGL(gemm1_kernel, dim3(8, 16, 2), dim3(256), 0, stream,
                       h2T, W2, t3p);
    hipLaunchKernelGGL(ln_relu_kernel, dim3(512), dim3(256), 0, stream,
                       t3p, b2, ln2g, ln2b, t3n);
    hipLaunchKernelGGL(gemm2_kernel, dim3(8, 4, 8), dim3(256), 0, stream,
                       t3n, Wo, t4p);
    hipLaunchKernelGGL(ln_out_kernel, dim3(512), dim3(256), 0, stream,
                       t4p, bo, lnog, lnob, out);
}